// Round 11
// baseline (66.394 us; speedup 1.0000x reference)
//
#include <hip/hip_runtime.h>
#include <hip/hip_bf16.h>
#include <hip/hip_fp16.h>

#define Bn 8
#define Cn 3
#define Tn 32
#define Hn 128
#define Wn 128
#define HWn (Hn * Wn)          // 16384
#define Nn (Tn * HWn)          // 524288 elems per (b,c)
#define EPSn 1e-5f
#define QT 2                   // 2-way t-split in k2 (16 outputs each)
#define SCH 128                // s-chunks per (b,c) in k2 (128 px each)
#define SSW (SCH * QT)         // 256 ss-partials per bc

__device__ __forceinline__ float silu_f(float v) {
    // fast silu: rcp intrinsic skips the div fixup sequence (absmax headroom ~10x)
    return v * __builtin_amdgcn_rcpf(1.0f + __expf(-v));
}

// ========== K1: spatial 3x3 conv (1->3ch) + SiLU -> y (fp16) ==========
// Block = 256 thr = 4 waves = 4 adjacent rows of one (b,t). Wave = row, 2 px/thread.
// No t-dependency -> embarrassingly parallel (8192 blocks), short dep chains.
__global__ __launch_bounds__(256) void k1_spatial(
    const float* __restrict__ x, const float* __restrict__ wsp,
    const float* __restrict__ bsp, __half* __restrict__ y)
{
    const int tid = threadIdx.x, lane = tid & 63, wave = tid >> 6;
    const int bt = blockIdx.x;          // 0..255
    const int b = bt >> 5, t = bt & 31;
    const int row = blockIdx.y * 4 + wave;
    const int col = lane * 2;

    float w[27], bb[3];
#pragma unroll
    for (int i = 0; i < 27; ++i) w[i] = wsp[i];
#pragma unroll
    for (int i = 0; i < 3; ++i) bb[i] = bsp[i];

    const float* xsl = x + ((size_t)b * Tn + t) * HWn + (size_t)row * Wn + col;
    const bool upok = row > 0, dnok = row < Hn - 1;
    float2 xm = upok ? *(const float2*)(xsl - Wn) : make_float2(0.f, 0.f);
    float2 xc = *(const float2*)(xsl);
    float2 xp = dnok ? *(const float2*)(xsl + Wn) : make_float2(0.f, 0.f);
    float xv[3][4];
    {
        float lu, rd;
        lu = __shfl_up(xm.y, 1);  rd = __shfl_down(xm.x, 1);
        xv[0][0] = (lane == 0) ? 0.f : lu; xv[0][1] = xm.x; xv[0][2] = xm.y;
        xv[0][3] = (lane == 63) ? 0.f : rd;
        lu = __shfl_up(xc.y, 1);  rd = __shfl_down(xc.x, 1);
        xv[1][0] = (lane == 0) ? 0.f : lu; xv[1][1] = xc.x; xv[1][2] = xc.y;
        xv[1][3] = (lane == 63) ? 0.f : rd;
        lu = __shfl_up(xp.y, 1);  rd = __shfl_down(xp.x, 1);
        xv[2][0] = (lane == 0) ? 0.f : lu; xv[2][1] = xp.x; xv[2][2] = xp.y;
        xv[2][3] = (lane == 63) ? 0.f : rd;
    }
#pragma unroll
    for (int c = 0; c < 3; ++c) {
        float s0 = bb[c], s1 = bb[c];
#pragma unroll
        for (int i = 0; i < 3; ++i) {
#pragma unroll
            for (int j = 0; j < 3; ++j) {
                const float wv = w[c * 9 + i * 3 + j];
                s0 += wv * xv[i][j];
                s1 += wv * xv[i][j + 1];
            }
        }
        __half2 o = __floats2half2_rn(silu_f(s0), silu_f(s1));
        *(__half2*)(y + ((size_t)(b * 3 + c) * Tn + t) * HWn + (size_t)row * Wn + col) = o;
    }
}

// ========== K2: temporal 7-tap conv from fp16 y + SiLU^2 + all analytics ==========
// Block = 128 thr = 2 waves; wave = one 128-px s-chunk of one (b,c), 2 px/thread.
// Pure streaming: ring 7xfloat2 (~35 VGPR), loads all independent, no spatial work.
// t split in 2 halves (3/2-slice halo, 19 slices read of 32).
// Outputs:
//   raw0/raw1[qt][bc][s]      = partial sum_t wks{0,1}[t]*g    (kv_s contraction)
//   pt0p/pt1p[bc][t][sch]     = per-chunk sum_s g*wkt{0,1}[s]  (kv_t contraction)
//   ss0p/ss1p[bc][sch*QT+qt]  = per-wave {sum g, sum g^2}      (SwitchNorm stats)
template<int QTg>
__device__ __forceinline__ void k2_body(
    const __half* __restrict__ y, const float* __restrict__ wtp,
    const float* __restrict__ btp, const float* __restrict__ wkt,
    const float* __restrict__ wks,
    float* __restrict__ raw0, float* __restrict__ raw1,
    float* __restrict__ pt0p, float* __restrict__ pt1p,
    float* __restrict__ ss0p, float* __restrict__ ss1p)
{
    constexpr int O0 = QTg * 16;
    constexpr int O1 = O0 + 16;
    constexpr int SLO = (O0 - 3 < 0) ? 0 : (O0 - 3);
    constexpr int SHI = (O1 + 2 > Tn - 1) ? (Tn - 1) : (O1 + 2);

    const int tid = threadIdx.x, lane = tid & 63, wave = tid >> 6;
    const int sch = blockIdx.x * 2 + wave;   // 0..127
    const int bc  = blockIdx.y;              // 0..23
    const int c = bc % 3;
    const int s0i = sch * 128 + lane * 2;

    float wt_r[7];
#pragma unroll
    for (int i = 0; i < 7; ++i) wt_r[i] = wtp[c * 7 + i];
    const float bt_r = btp[c];

    const __half* yb = y + (size_t)bc * Nn + s0i;
    const float2 k0v = *(const float2*)(wkt + s0i);
    const float2 k1v = *(const float2*)(wkt + HWn + s0i);

    float2 ring[7];
    float2 a0 = make_float2(0.f, 0.f), a1 = make_float2(0.f, 0.f);
    float ps = 0.f, pq = 0.f;

#pragma unroll
    for (int tt = SLO; tt <= SHI + 3; ++tt) {
        if (tt <= SHI) {
            const __half2 hv = *(const __half2*)(yb + (size_t)tt * HWn);
            ring[tt % 7] = __half22float2(hv);
        }
        const int to = tt - 3;
        if (to >= O0 && to < O1) {          // compile-time pruned per unrolled iter
            float t0 = bt_r, t1 = bt_r;
#pragma unroll
            for (int k = 0; k < 7; ++k) {
                const int ts = to + k - 3;
                if (ts >= 0 && ts < Tn) {   // compile-time
                    const float wv = wt_r[k];
                    t0 += wv * ring[ts % 7].x;
                    t1 += wv * ring[ts % 7].y;
                }
            }
            const float g0 = silu_f(silu_f(t0));
            const float g1 = silu_f(silu_f(t1));
            const float wk0 = wks[to];      // uniform scalar loads
            const float wk1 = wks[Tn + to];
            a0.x += wk0 * g0; a0.y += wk0 * g1;
            a1.x += wk1 * g0; a1.y += wk1 * g1;
            ps += g0 + g1;
            pq += g0 * g0 + g1 * g1;
            // 2-value packed wave reduce: 3 xor stages in 8-groups, parity select,
            // 3 more stages -> lane0 = total p0, lane1 = total p1.
            float p0 = k0v.x * g0 + k0v.y * g1;
            float p1 = k1v.x * g0 + k1v.y * g1;
            p0 += __shfl_xor(p0, 1, 64); p0 += __shfl_xor(p0, 2, 64); p0 += __shfl_xor(p0, 4, 64);
            p1 += __shfl_xor(p1, 1, 64); p1 += __shfl_xor(p1, 2, 64); p1 += __shfl_xor(p1, 4, 64);
            float r = (lane & 1) ? p1 : p0;
            r += __shfl_xor(r, 8, 64);
            r += __shfl_xor(r, 16, 64);
            r += __shfl_xor(r, 32, 64);
            if (lane < 2) {
                float* dst = lane ? pt1p : pt0p;
                dst[((size_t)bc * Tn + to) * SCH + sch] = r;
            }
        }
    }

    // --- wave-reduce ps/pq via the same packed trick ---
    {
        float p0 = ps, p1 = pq;
        p0 += __shfl_xor(p0, 1, 64); p0 += __shfl_xor(p0, 2, 64); p0 += __shfl_xor(p0, 4, 64);
        p1 += __shfl_xor(p1, 1, 64); p1 += __shfl_xor(p1, 2, 64); p1 += __shfl_xor(p1, 4, 64);
        float r = (lane & 1) ? p1 : p0;
        r += __shfl_xor(r, 8, 64);
        r += __shfl_xor(r, 16, 64);
        r += __shfl_xor(r, 32, 64);
        if (lane == 0) ss0p[(size_t)bc * SSW + sch * QT + QTg] = r;
        if (lane == 1) ss1p[(size_t)bc * SSW + sch * QT + QTg] = r;
    }
    // --- raw kv_s stores (per-half buffers) ---
    {
        const size_t off = (size_t)(QTg * 24 + bc) * HWn + s0i;
        *(float2*)(raw0 + off) = a0;
        *(float2*)(raw1 + off) = a1;
    }
}

__global__ __launch_bounds__(128) void k2_temporal(
    const __half* __restrict__ y, const float* __restrict__ wtp,
    const float* __restrict__ btp, const float* __restrict__ wkt,
    const float* __restrict__ wks,
    float* __restrict__ raw0, float* __restrict__ raw1,
    float* __restrict__ pt0p, float* __restrict__ pt1p,
    float* __restrict__ ss0p, float* __restrict__ ss1p)
{
    if (blockIdx.z == 0)
        k2_body<0>(y, wtp, btp, wkt, wks, raw0, raw1, pt0p, pt1p, ss0p, ss1p);
    else
        k2_body<1>(y, wtp, btp, wkt, wks, raw0, raw1, pt0p, pt1p, ss0p, ss1p);
}

// ========== K3a: parallel reduction of pt/ss partials + wkt/wks sums ==========
// blocks 0..23: per-bc reduce; block 24: weight sums.
__global__ __launch_bounds__(256) void k3a_reduce(
    const float* __restrict__ pt0p, const float* __restrict__ pt1p,
    const float* __restrict__ ss0p, const float* __restrict__ ss1p,
    const float* __restrict__ wkt, const float* __restrict__ wks,
    float* __restrict__ kvt0r, float* __restrict__ kvt1r,
    float* __restrict__ ssS, float* __restrict__ ssSS, float* __restrict__ wsum)
{
    const int blk = blockIdx.x;
    const int tid = threadIdx.x;
    if (blk < Bn * Cn) {
        // pt reduce: 32 t-rows of SCH=128; 8 threads per t
        const int t = tid >> 3, g = tid & 7;
        const float4* p0 = (const float4*)(pt0p + ((size_t)blk * Tn + t) * SCH) + g * 4;
        const float4* p1 = (const float4*)(pt1p + ((size_t)blk * Tn + t) * SCH) + g * 4;
        float4 A0 = p0[0], A1 = p0[1], A2 = p0[2], A3 = p0[3];
        float4 B0 = p1[0], B1 = p1[1], B2 = p1[2], B3 = p1[3];
        float s0 = ((A0.x + A0.y) + (A0.z + A0.w)) + ((A1.x + A1.y) + (A1.z + A1.w))
                 + ((A2.x + A2.y) + (A2.z + A2.w)) + ((A3.x + A3.y) + (A3.z + A3.w));
        float s1 = ((B0.x + B0.y) + (B0.z + B0.w)) + ((B1.x + B1.y) + (B1.z + B1.w))
                 + ((B2.x + B2.y) + (B2.z + B2.w)) + ((B3.x + B3.y) + (B3.z + B3.w));
        s0 += __shfl_xor(s0, 1, 64); s0 += __shfl_xor(s0, 2, 64); s0 += __shfl_xor(s0, 4, 64);
        s1 += __shfl_xor(s1, 1, 64); s1 += __shfl_xor(s1, 2, 64); s1 += __shfl_xor(s1, 4, 64);
        if (g == 0) { kvt0r[blk * Tn + t] = s0; kvt1r[blk * Tn + t] = s1; }
        // ss reduce: SSW=256 floats each array (64 float4)
        const float4* q0 = (const float4*)(ss0p + (size_t)blk * SSW);
        const float4* q1 = (const float4*)(ss1p + (size_t)blk * SSW);
        float a = 0.f, bb = 0.f;
        if (tid < SSW / 4) {
            float4 a4 = q0[tid], b4 = q1[tid];
            a = (a4.x + a4.y) + (a4.z + a4.w);
            bb = (b4.x + b4.y) + (b4.z + b4.w);
        }
        __shared__ float r0[256], r1[256];
        r0[tid] = a; r1[tid] = bb;
        __syncthreads();
        for (int off = 128; off > 0; off >>= 1) {
            if (tid < off) { r0[tid] += r0[tid + off]; r1[tid] += r1[tid + off]; }
            __syncthreads();
        }
        if (tid == 0) { ssS[blk] = r0[0]; ssSS[blk] = r1[0]; }
    } else {
        // wkt sums (2 x 16384) and wks sums (2 x 32)
        const float4* w0 = (const float4*)wkt;
        const float4* w1 = (const float4*)(wkt + HWn);
        float l0 = 0.f, l1 = 0.f;
        for (int i = tid; i < HWn / 4; i += 256) {
            float4 t0 = w0[i], t1 = w1[i];
            l0 += (t0.x + t0.y) + (t0.z + t0.w);
            l1 += (t1.x + t1.y) + (t1.z + t1.w);
        }
        __shared__ float r0[256], r1[256];
        r0[tid] = l0; r1[tid] = l1;
        __syncthreads();
        for (int off = 128; off > 0; off >>= 1) {
            if (tid < off) { r0[tid] += r0[tid + off]; r1[tid] += r1[tid + off]; }
            __syncthreads();
        }
        if (tid == 0) { wsum[0] = r0[0]; wsum[1] = r1[0]; }
        if (tid < 64) {
            float v = wks[tid];   // lanes 0..31 hold wks0, 32..63 hold wks1
            v += __shfl_xor(v, 1, 64); v += __shfl_xor(v, 2, 64);
            v += __shfl_xor(v, 4, 64); v += __shfl_xor(v, 8, 64);
            v += __shfl_xor(v, 16, 64);
            if (tid == 0) wsum[2] = v;
            if (tid == 32) wsum[3] = v;
        }
    }
}

// ========== K3b: SwitchNorm stats + kv_t softmax -> A, scale/shift (tiny) ==========
__global__ __launch_bounds__(256) void k3b_finalize(
    const float* __restrict__ kvt0r, const float* __restrict__ kvt1r,
    const float* __restrict__ ssS, const float* __restrict__ ssSS,
    const float* __restrict__ mean_w, const float* __restrict__ var_w,
    const float* __restrict__ snw, const float* __restrict__ snb,
    const float* __restrict__ wsum,
    float* __restrict__ scale, float* __restrict__ shift, float* __restrict__ A)
{
    const int tid = threadIdx.x;
    __shared__ float kvt0[Bn * Cn * Tn], kvt1[Bn * Cn * Tn];
    __shared__ float sW[4];
    for (int i = tid; i < Bn * Cn * Tn; i += 256) { kvt0[i] = kvt0r[i]; kvt1[i] = kvt1r[i]; }
    if (tid < 4) sW[tid] = wsum[tid];
    __shared__ float sh_mean[24], sh_var[24], sh_temp[24];
    __shared__ float sh_mln[8], sh_vln[8], sh_mbn[3], sh_vbn[3];
    __shared__ float sh_mw[3], sh_vw[3];
    __shared__ float sh_scale[24], sh_shift[24];
    if (tid < 24) {
        float S = ssS[tid], SS = ssSS[tid];
        const float Nf = (float)Nn;
        float mean = S / Nf;
        float var = (SS - S * mean) / (Nf - 1.0f);   // unbiased (ddof=1)
        sh_mean[tid] = mean; sh_var[tid] = var; sh_temp[tid] = var + mean * mean;
    }
    __syncthreads();
    if (tid == 0) {
        for (int b = 0; b < Bn; ++b) {
            float m = 0.f, tp = 0.f;
            for (int c = 0; c < Cn; ++c) { m += sh_mean[b * 3 + c]; tp += sh_temp[b * 3 + c]; }
            m *= (1.0f / 3.0f); tp *= (1.0f / 3.0f);
            sh_mln[b] = m; sh_vln[b] = tp - m * m;
        }
        for (int c = 0; c < Cn; ++c) {
            float m = 0.f, tp = 0.f;
            for (int b = 0; b < Bn; ++b) { m += sh_mean[b * 3 + c]; tp += sh_temp[b * 3 + c]; }
            m *= 0.125f; tp *= 0.125f;
            sh_mbn[c] = m; sh_vbn[c] = tp - m * m;
        }
        {
            float m0 = mean_w[0], m1 = mean_w[1], m2 = mean_w[2];
            float mm = fmaxf(m0, fmaxf(m1, m2));
            float e0 = __expf(m0 - mm), e1 = __expf(m1 - mm), e2 = __expf(m2 - mm);
            float inv = 1.0f / (e0 + e1 + e2);
            sh_mw[0] = e0 * inv; sh_mw[1] = e1 * inv; sh_mw[2] = e2 * inv;
        }
        {
            float v0 = var_w[0], v1 = var_w[1], v2 = var_w[2];
            float vm = fmaxf(v0, fmaxf(v1, v2));
            float e0 = __expf(v0 - vm), e1 = __expf(v1 - vm), e2 = __expf(v2 - vm);
            float inv = 1.0f / (e0 + e1 + e2);
            sh_vw[0] = e0 * inv; sh_vw[1] = e1 * inv; sh_vw[2] = e2 * inv;
        }
    }
    __syncthreads();
    if (tid < 24) {
        int b = tid / 3, c = tid % 3;
        float mean = sh_mw[0] * sh_mean[tid] + sh_mw[1] * sh_mln[b] + sh_mw[2] * sh_mbn[c];
        float var  = sh_vw[0] * sh_var[tid]  + sh_vw[1] * sh_vln[b] + sh_vw[2] * sh_vbn[c];
        float inv = 1.0f / sqrtf(var + EPSn);
        float sc = inv * snw[c];
        float sf = snb[c] - mean * sc;
        sh_scale[tid] = sc; sh_shift[tid] = sf;
        scale[tid] = sc; shift[tid] = sf;
    }
    __syncthreads();
    for (int i = tid; i < Bn * Cn * Tn; i += 256) {
        int bc = i >> 5;
        kvt0[i] = sh_scale[bc] * kvt0[i] + sh_shift[bc] * sW[0];
        kvt1[i] = sh_scale[bc] * kvt1[i] + sh_shift[bc] * sW[1];
    }
    __syncthreads();
    if (tid < 24) {
        float m = -3.4e38f;
        for (int t = 0; t < Tn; ++t) m = fmaxf(m, kvt0[tid * Tn + t]);
        float se = 0.f;
        for (int t = 0; t < Tn; ++t) se += __expf(kvt0[tid * Tn + t] - m);
        float inv = 1.0f / se;
        for (int t = 0; t < Tn; ++t)
            A[tid * Tn + t] = sqrtf(__expf(kvt0[tid * Tn + t] - m) * inv) * kvt1[tid * Tn + t];
    }
}

// ========== K5a: reduce raw halves + affine; chunk max/expsum -> v0s/v1s, ms ==========
__global__ __launch_bounds__(256) void k5a_maxsum(
    const float* __restrict__ raw0, const float* __restrict__ raw1,
    const float* __restrict__ scale, const float* __restrict__ shift,
    const float* __restrict__ wsum, float* __restrict__ v0s,
    float* __restrict__ v1s, float2* __restrict__ ms)
{
    const int ch = blockIdx.x;   // 0..7 (chunks of 2048)
    const int bc = blockIdx.y;   // 0..23
    const int tid = threadIdx.x, lane = tid & 63, wave = tid >> 6;
    const float sc = scale[bc], sf = shift[bc];
    const float c0 = sf * wsum[2], c1 = sf * wsum[3];
    const size_t idx = (size_t)bc * HWn + ch * 2048 + tid * 8;
    float4 r0a = make_float4(0.f, 0.f, 0.f, 0.f), r0b = r0a, r1a = r0a, r1b = r0a;
#pragma unroll
    for (int q = 0; q < QT; ++q) {
        const float* p0 = raw0 + (size_t)q * 24 * HWn + idx;
        const float* p1 = raw1 + (size_t)q * 24 * HWn + idx;
        float4 t0 = ((const float4*)p0)[0], t1 = ((const float4*)p0)[1];
        float4 u0 = ((const float4*)p1)[0], u1 = ((const float4*)p1)[1];
        r0a.x += t0.x; r0a.y += t0.y; r0a.z += t0.z; r0a.w += t0.w;
        r0b.x += t1.x; r0b.y += t1.y; r0b.z += t1.z; r0b.w += t1.w;
        r1a.x += u0.x; r1a.y += u0.y; r1a.z += u0.z; r1a.w += u0.w;
        r1b.x += u1.x; r1b.y += u1.y; r1b.z += u1.z; r1b.w += u1.w;
    }
    float v0[8] = { sc * r0a.x + c0, sc * r0a.y + c0, sc * r0a.z + c0, sc * r0a.w + c0,
                    sc * r0b.x + c0, sc * r0b.y + c0, sc * r0b.z + c0, sc * r0b.w + c0 };
    float v1[8] = { sc * r1a.x + c1, sc * r1a.y + c1, sc * r1a.z + c1, sc * r1a.w + c1,
                    sc * r1b.x + c1, sc * r1b.y + c1, sc * r1b.z + c1, sc * r1b.w + c1 };
    ((float4*)(v0s + idx))[0] = make_float4(v0[0], v0[1], v0[2], v0[3]);
    ((float4*)(v0s + idx))[1] = make_float4(v0[4], v0[5], v0[6], v0[7]);
    ((float4*)(v1s + idx))[0] = make_float4(v1[0], v1[1], v1[2], v1[3]);
    ((float4*)(v1s + idx))[1] = make_float4(v1[4], v1[5], v1[6], v1[7]);
    float m = -3.4e38f;
#pragma unroll
    for (int i = 0; i < 8; ++i) m = fmaxf(m, v0[i]);
#pragma unroll
    for (int d = 1; d < 64; d <<= 1) m = fmaxf(m, __shfl_xor(m, d, 64));
    __shared__ float wm[4], wsm[4];
    if (lane == 0) wm[wave] = m;
    __syncthreads();
    const float M = fmaxf(fmaxf(wm[0], wm[1]), fmaxf(wm[2], wm[3]));
    float s = 0.f;
#pragma unroll
    for (int i = 0; i < 8; ++i) s += __expf(v0[i] - M);
#pragma unroll
    for (int d = 1; d < 64; d <<= 1) s += __shfl_xor(s, d, 64);
    if (lane == 0) wsm[wave] = s;
    __syncthreads();
    if (tid == 0) {
        float2 o; o.x = M; o.y = wsm[0] + wsm[1] + wsm[2] + wsm[3];
        ms[bc * 8 + ch] = o;
    }
}

// ========== K6: B finalize inline + outer product out[bc,t,s] = A[t]*B[s] ==========
__global__ __launch_bounds__(256) void k6_outer(
    const float* __restrict__ v0s, const float* __restrict__ v1s,
    const float2* __restrict__ ms, const float* __restrict__ A,
    float* __restrict__ out)
{
    const int ch = blockIdx.x;   // 0..15 (chunks of 1024)
    const int bc = blockIdx.y;   // 0..23
    const int tid = threadIdx.x;
    __shared__ float a[Tn];
    if (tid < Tn) a[tid] = A[bc * Tn + tid];
    float M = -3.4e38f;
#pragma unroll
    for (int j = 0; j < 8; ++j) M = fmaxf(M, ms[bc * 8 + j].x);
    float S = 0.f;
#pragma unroll
    for (int j = 0; j < 8; ++j) S += ms[bc * 8 + j].y * __expf(ms[bc * 8 + j].x - M);
    const float invS = __builtin_amdgcn_rcpf(S);
    const int s = ch * 1024 + tid * 4;
    float4 r0 = *(const float4*)(v0s + (size_t)bc * HWn + s);
    float4 r1 = *(const float4*)(v1s + (size_t)bc * HWn + s);
    float4 Bv;
    Bv.x = sqrtf(__expf(r0.x - M) * invS) * r1.x;
    Bv.y = sqrtf(__expf(r0.y - M) * invS) * r1.y;
    Bv.z = sqrtf(__expf(r0.z - M) * invS) * r1.z;
    Bv.w = sqrtf(__expf(r0.w - M) * invS) * r1.w;
    __syncthreads();
    float* op = out + (size_t)bc * Nn + s;
#pragma unroll
    for (int t = 0; t < Tn; ++t) {
        const float av = a[t];
        float4 o; o.x = av * Bv.x; o.y = av * Bv.y; o.z = av * Bv.z; o.w = av * Bv.w;
        *(float4*)(op + (size_t)t * HWn) = o;
    }
}

extern "C" void kernel_launch(void* const* d_in, const int* in_sizes, int n_in,
                              void* d_out, int out_size, void* d_ws, size_t ws_size,
                              hipStream_t stream) {
    const float* x          = (const float*)d_in[0];
    const float* w_spatial  = (const float*)d_in[1];
    const float* b_spatial  = (const float*)d_in[2];
    const float* w_temporal = (const float*)d_in[3];
    const float* b_temporal = (const float*)d_in[4];
    const float* sn_weight  = (const float*)d_in[5];
    const float* sn_bias    = (const float*)d_in[6];
    const float* mean_weight= (const float*)d_in[7];
    const float* var_weight = (const float*)d_in[8];
    const float* w_kv_s     = (const float*)d_in[9];
    const float* w_kv_t     = (const float*)d_in[10];
    float* out = (float*)d_out;
    float* ws  = (float*)d_ws;

    // ws layout (floats) — y staged in fp16 (halves the round-trip)
    __half* yh   = (__half*)ws;                          // 12,582,912 halves = 6,291,456 f
    float* raw0  = ws + 6291456;                         // [QT][24][HWn] = 786432
    float* raw1  = raw0 + (size_t)QT * Bn * Cn * HWn;    // 786432
    float* pt0p  = raw1 + (size_t)QT * Bn * Cn * HWn;    // 24*32*128 = 98304
    float* pt1p  = pt0p + (size_t)Bn * Cn * Tn * SCH;    // 98304
    float* ss0p  = pt1p + (size_t)Bn * Cn * Tn * SCH;    // 24*256 = 6144
    float* ss1p  = ss0p + (size_t)Bn * Cn * SSW;         // 6144
    float* v0s   = ss1p + (size_t)Bn * Cn * SSW;         // 24*HWn = 393216
    float* v1s   = v0s + (size_t)Bn * Cn * HWn;          // 393216
    float* kvt0r = v1s + (size_t)Bn * Cn * HWn;          // 768
    float* kvt1r = kvt0r + Bn * Cn * Tn;                 // 768
    float* ssS   = kvt1r + Bn * Cn * Tn;                 // 24
    float* ssSS  = ssS + 24;                             // 24
    float* scale = ssSS + 24;                            // 24
    float* shift = scale + 24;                           // 24
    float* A     = shift + 24;                           // 768
    float* wsum  = A + Bn * Cn * Tn;                     // 4
    float2* ms   = (float2*)(wsum + 4);                  // 192 float2

    k1_spatial<<<dim3(Bn * Tn, Hn / 4), 256, 0, stream>>>(x, w_spatial, b_spatial, yh);
    k2_temporal<<<dim3(SCH / 2, Bn * Cn, QT), 128, 0, stream>>>(yh, w_temporal,
                                                                b_temporal, w_kv_t,
                                                                w_kv_s, raw0, raw1,
                                                                pt0p, pt1p, ss0p, ss1p);
    k3a_reduce<<<Bn * Cn + 1, 256, 0, stream>>>(pt0p, pt1p, ss0p, ss1p, w_kv_t, w_kv_s,
                                                kvt0r, kvt1r, ssS, ssSS, wsum);
    k3b_finalize<<<1, 256, 0, stream>>>(kvt0r, kvt1r, ssS, ssSS,
                                        mean_weight, var_weight, sn_weight, sn_bias,
                                        wsum, scale, shift, A);
    k5a_maxsum<<<dim3(8, Bn * Cn), 256, 0, stream>>>(raw0, raw1, scale, shift, wsum,
                                                     v0s, v1s, ms);
    k6_outer<<<dim3(16, Bn * Cn), 256, 0, stream>>>(v0s, v1s, ms, A, out);
}

// Round 12
// 63.611 us; speedup vs baseline: 1.0438x; 1.0438x over previous
//
#include <hip/hip_runtime.h>
#include <hip/hip_bf16.h>
#include <hip/hip_fp16.h>

#define Bn 8
#define Cn 3
#define Tn 32
#define Hn 128
#define Wn 128
#define HWn (Hn * Wn)          // 16384
#define Nn (Tn * HWn)          // 524288 elems per (b,c)
#define EPSn 1e-5f
#define QT 2                   // 2-way t-split in k2 (16 outputs each)
#define SCH 128                // s-chunks per (b,c) in k2 (128 px each)
#define SSW (SCH * QT)         // 256 ss-partials per bc

__device__ __forceinline__ float silu_f(float v) {
    // fast silu: rcp intrinsic skips the div fixup sequence (absmax headroom ~12x)
    return v * __builtin_amdgcn_rcpf(1.0f + __expf(-v));
}

// ========== K1: spatial 3x3 conv (1->3ch) + SiLU -> y (fp16), 4 px/thread ==========
// Block = 256 thr = 4 waves = 8 rows of one (b,t); 32 lanes x 4 px cover a row.
// Lane-group boundary == image W boundary, so the shfl halo is exact.
__global__ __launch_bounds__(256) void k1_spatial(
    const float* __restrict__ x, const float* __restrict__ wsp,
    const float* __restrict__ bsp, __half* __restrict__ y)
{
    const int tid = threadIdx.x;
    const int sub = tid & 31;           // 32 lane-groups of 4 px
    const int bt = blockIdx.x;          // 0..255
    const int b = bt >> 5, t = bt & 31;
    const int row = blockIdx.y * 8 + (tid >> 5);
    const int col = sub * 4;

    float w[27], bb[3];
#pragma unroll
    for (int i = 0; i < 27; ++i) w[i] = wsp[i];
#pragma unroll
    for (int i = 0; i < 3; ++i) bb[i] = bsp[i];

    const float* xsl = x + ((size_t)b * Tn + t) * HWn + (size_t)row * Wn + col;
    const bool upok = row > 0, dnok = row < Hn - 1;
    const float4 z4 = make_float4(0.f, 0.f, 0.f, 0.f);
    float4 xm = upok ? *(const float4*)(xsl - Wn) : z4;
    float4 xc = *(const float4*)(xsl);
    float4 xp = dnok ? *(const float4*)(xsl + Wn) : z4;
    float xv[3][6];
    {
        float lu, rd;
        lu = __shfl_up(xm.w, 1);  rd = __shfl_down(xm.x, 1);
        xv[0][0] = (sub == 0) ? 0.f : lu; xv[0][1] = xm.x; xv[0][2] = xm.y;
        xv[0][3] = xm.z; xv[0][4] = xm.w; xv[0][5] = (sub == 31) ? 0.f : rd;
        lu = __shfl_up(xc.w, 1);  rd = __shfl_down(xc.x, 1);
        xv[1][0] = (sub == 0) ? 0.f : lu; xv[1][1] = xc.x; xv[1][2] = xc.y;
        xv[1][3] = xc.z; xv[1][4] = xc.w; xv[1][5] = (sub == 31) ? 0.f : rd;
        lu = __shfl_up(xp.w, 1);  rd = __shfl_down(xp.x, 1);
        xv[2][0] = (sub == 0) ? 0.f : lu; xv[2][1] = xp.x; xv[2][2] = xp.y;
        xv[2][3] = xp.z; xv[2][4] = xp.w; xv[2][5] = (sub == 31) ? 0.f : rd;
    }
#pragma unroll
    for (int c = 0; c < 3; ++c) {
        float s0 = bb[c], s1 = bb[c], s2 = bb[c], s3 = bb[c];
#pragma unroll
        for (int i = 0; i < 3; ++i) {
#pragma unroll
            for (int j = 0; j < 3; ++j) {
                const float wv = w[c * 9 + i * 3 + j];
                s0 += wv * xv[i][j];
                s1 += wv * xv[i][j + 1];
                s2 += wv * xv[i][j + 2];
                s3 += wv * xv[i][j + 3];
            }
        }
        __half2 o01 = __floats2half2_rn(silu_f(s0), silu_f(s1));
        __half2 o23 = __floats2half2_rn(silu_f(s2), silu_f(s3));
        __half2* dst = (__half2*)(y + ((size_t)(b * 3 + c) * Tn + t) * HWn
                                  + (size_t)row * Wn + col);
        dst[0] = o01; dst[1] = o23;
    }
}

// ========== K2: temporal 7-tap conv from fp16 y + SiLU^2 + all analytics ==========
// Block = 128 thr = 2 waves; wave = one 128-px s-chunk of one (b,c), 2 px/thread.
// Outputs:
//   raw0/raw1[qt][bc][s]      = partial sum_t wks{0,1}[t]*g    (kv_s contraction)
//   pt0p/pt1p[bc][t][sch]     = per-chunk sum_s g*wkt{0,1}[s]  (kv_t contraction)
//   ss0p/ss1p[bc][sch*QT+qt]  = per-wave {sum g, sum g^2}      (SwitchNorm stats)
template<int QTg>
__device__ __forceinline__ void k2_body(
    const __half* __restrict__ y, const float* __restrict__ wtp,
    const float* __restrict__ btp, const float* __restrict__ wkt,
    const float* __restrict__ wks,
    float* __restrict__ raw0, float* __restrict__ raw1,
    float* __restrict__ pt0p, float* __restrict__ pt1p,
    float* __restrict__ ss0p, float* __restrict__ ss1p)
{
    constexpr int O0 = QTg * 16;
    constexpr int O1 = O0 + 16;
    constexpr int SLO = (O0 - 3 < 0) ? 0 : (O0 - 3);
    constexpr int SHI = (O1 + 2 > Tn - 1) ? (Tn - 1) : (O1 + 2);

    const int tid = threadIdx.x, lane = tid & 63, wave = tid >> 6;
    const int sch = blockIdx.x * 2 + wave;   // 0..127
    const int bc  = blockIdx.y;              // 0..23
    const int c = bc % 3;
    const int s0i = sch * 128 + lane * 2;

    float wt_r[7];
#pragma unroll
    for (int i = 0; i < 7; ++i) wt_r[i] = wtp[c * 7 + i];
    const float bt_r = btp[c];

    const __half* yb = y + (size_t)bc * Nn + s0i;
    const float2 k0v = *(const float2*)(wkt + s0i);
    const float2 k1v = *(const float2*)(wkt + HWn + s0i);

    float2 ring[7];
    float2 a0 = make_float2(0.f, 0.f), a1 = make_float2(0.f, 0.f);
    float ps = 0.f, pq = 0.f;

#pragma unroll
    for (int tt = SLO; tt <= SHI + 3; ++tt) {
        if (tt <= SHI) {
            const __half2 hv = *(const __half2*)(yb + (size_t)tt * HWn);
            ring[tt % 7] = __half22float2(hv);
        }
        const int to = tt - 3;
        if (to >= O0 && to < O1) {          // compile-time pruned per unrolled iter
            float t0 = bt_r, t1 = bt_r;
#pragma unroll
            for (int k = 0; k < 7; ++k) {
                const int ts = to + k - 3;
                if (ts >= 0 && ts < Tn) {   // compile-time
                    const float wv = wt_r[k];
                    t0 += wv * ring[ts % 7].x;
                    t1 += wv * ring[ts % 7].y;
                }
            }
            const float g0 = silu_f(silu_f(t0));
            const float g1 = silu_f(silu_f(t1));
            const float wk0 = wks[to];      // uniform scalar loads
            const float wk1 = wks[Tn + to];
            a0.x += wk0 * g0; a0.y += wk0 * g1;
            a1.x += wk1 * g0; a1.y += wk1 * g1;
            ps += g0 + g1;
            pq += g0 * g0 + g1 * g1;
            // 2-value packed wave reduce
            float p0 = k0v.x * g0 + k0v.y * g1;
            float p1 = k1v.x * g0 + k1v.y * g1;
            p0 += __shfl_xor(p0, 1, 64); p0 += __shfl_xor(p0, 2, 64); p0 += __shfl_xor(p0, 4, 64);
            p1 += __shfl_xor(p1, 1, 64); p1 += __shfl_xor(p1, 2, 64); p1 += __shfl_xor(p1, 4, 64);
            float r = (lane & 1) ? p1 : p0;
            r += __shfl_xor(r, 8, 64);
            r += __shfl_xor(r, 16, 64);
            r += __shfl_xor(r, 32, 64);
            if (lane < 2) {
                float* dst = lane ? pt1p : pt0p;
                dst[((size_t)bc * Tn + to) * SCH + sch] = r;
            }
        }
    }

    // --- wave-reduce ps/pq via the same packed trick ---
    {
        float p0 = ps, p1 = pq;
        p0 += __shfl_xor(p0, 1, 64); p0 += __shfl_xor(p0, 2, 64); p0 += __shfl_xor(p0, 4, 64);
        p1 += __shfl_xor(p1, 1, 64); p1 += __shfl_xor(p1, 2, 64); p1 += __shfl_xor(p1, 4, 64);
        float r = (lane & 1) ? p1 : p0;
        r += __shfl_xor(r, 8, 64);
        r += __shfl_xor(r, 16, 64);
        r += __shfl_xor(r, 32, 64);
        if (lane == 0) ss0p[(size_t)bc * SSW + sch * QT + QTg] = r;
        if (lane == 1) ss1p[(size_t)bc * SSW + sch * QT + QTg] = r;
    }
    // --- raw kv_s stores (per-half buffers) ---
    {
        const size_t off = (size_t)(QTg * 24 + bc) * HWn + s0i;
        *(float2*)(raw0 + off) = a0;
        *(float2*)(raw1 + off) = a1;
    }
}

__global__ __launch_bounds__(128) void k2_temporal(
    const __half* __restrict__ y, const float* __restrict__ wtp,
    const float* __restrict__ btp, const float* __restrict__ wkt,
    const float* __restrict__ wks,
    float* __restrict__ raw0, float* __restrict__ raw1,
    float* __restrict__ pt0p, float* __restrict__ pt1p,
    float* __restrict__ ss0p, float* __restrict__ ss1p)
{
    if (blockIdx.z == 0)
        k2_body<0>(y, wtp, btp, wkt, wks, raw0, raw1, pt0p, pt1p, ss0p, ss1p);
    else
        k2_body<1>(y, wtp, btp, wkt, wks, raw0, raw1, pt0p, pt1p, ss0p, ss1p);
}

// ========== K3a: parallel reduction of pt/ss partials + wkt/wks sums ==========
__global__ __launch_bounds__(256) void k3a_reduce(
    const float* __restrict__ pt0p, const float* __restrict__ pt1p,
    const float* __restrict__ ss0p, const float* __restrict__ ss1p,
    const float* __restrict__ wkt, const float* __restrict__ wks,
    float* __restrict__ kvt0r, float* __restrict__ kvt1r,
    float* __restrict__ ssS, float* __restrict__ ssSS, float* __restrict__ wsum)
{
    const int blk = blockIdx.x;
    const int tid = threadIdx.x;
    if (blk < Bn * Cn) {
        const int t = tid >> 3, g = tid & 7;
        const float4* p0 = (const float4*)(pt0p + ((size_t)blk * Tn + t) * SCH) + g * 4;
        const float4* p1 = (const float4*)(pt1p + ((size_t)blk * Tn + t) * SCH) + g * 4;
        float4 A0 = p0[0], A1 = p0[1], A2 = p0[2], A3 = p0[3];
        float4 B0 = p1[0], B1 = p1[1], B2 = p1[2], B3 = p1[3];
        float s0 = ((A0.x + A0.y) + (A0.z + A0.w)) + ((A1.x + A1.y) + (A1.z + A1.w))
                 + ((A2.x + A2.y) + (A2.z + A2.w)) + ((A3.x + A3.y) + (A3.z + A3.w));
        float s1 = ((B0.x + B0.y) + (B0.z + B0.w)) + ((B1.x + B1.y) + (B1.z + B1.w))
                 + ((B2.x + B2.y) + (B2.z + B2.w)) + ((B3.x + B3.y) + (B3.z + B3.w));
        s0 += __shfl_xor(s0, 1, 64); s0 += __shfl_xor(s0, 2, 64); s0 += __shfl_xor(s0, 4, 64);
        s1 += __shfl_xor(s1, 1, 64); s1 += __shfl_xor(s1, 2, 64); s1 += __shfl_xor(s1, 4, 64);
        if (g == 0) { kvt0r[blk * Tn + t] = s0; kvt1r[blk * Tn + t] = s1; }
        // ss reduce: SSW=256 floats each array (64 float4)
        const float4* q0 = (const float4*)(ss0p + (size_t)blk * SSW);
        const float4* q1 = (const float4*)(ss1p + (size_t)blk * SSW);
        float a = 0.f, bb = 0.f;
        if (tid < SSW / 4) {
            float4 a4 = q0[tid], b4 = q1[tid];
            a = (a4.x + a4.y) + (a4.z + a4.w);
            bb = (b4.x + b4.y) + (b4.z + b4.w);
        }
        __shared__ float r0[256], r1[256];
        r0[tid] = a; r1[tid] = bb;
        __syncthreads();
        for (int off = 128; off > 0; off >>= 1) {
            if (tid < off) { r0[tid] += r0[tid + off]; r1[tid] += r1[tid + off]; }
            __syncthreads();
        }
        if (tid == 0) { ssS[blk] = r0[0]; ssSS[blk] = r1[0]; }
    } else {
        const float4* w0 = (const float4*)wkt;
        const float4* w1 = (const float4*)(wkt + HWn);
        float l0 = 0.f, l1 = 0.f;
        for (int i = tid; i < HWn / 4; i += 256) {
            float4 t0 = w0[i], t1 = w1[i];
            l0 += (t0.x + t0.y) + (t0.z + t0.w);
            l1 += (t1.x + t1.y) + (t1.z + t1.w);
        }
        __shared__ float r0[256], r1[256];
        r0[tid] = l0; r1[tid] = l1;
        __syncthreads();
        for (int off = 128; off > 0; off >>= 1) {
            if (tid < off) { r0[tid] += r0[tid + off]; r1[tid] += r1[tid + off]; }
            __syncthreads();
        }
        if (tid == 0) { wsum[0] = r0[0]; wsum[1] = r1[0]; }
        if (tid < 64) {
            float v = wks[tid];
            v += __shfl_xor(v, 1, 64); v += __shfl_xor(v, 2, 64);
            v += __shfl_xor(v, 4, 64); v += __shfl_xor(v, 8, 64);
            v += __shfl_xor(v, 16, 64);
            if (tid == 0) wsum[2] = v;
            if (tid == 32) wsum[3] = v;
        }
    }
}

// ========== K6: inline stats + A-softmax + s-softmax + outer product ==========
// Block (ch, bc): recomputes the tiny SwitchNorm stats + own A-row inline (uniform,
// redundant across blocks — ~200 scalar ops), sweeps raw halves for the s-softmax
// max/expsum (128 KB, L2-shared among the 16 blocks of this bc), then writes its
// 1024-px slice of out = A[t]*B[s].
__global__ __launch_bounds__(256) void k6_fused(
    const float* __restrict__ raw0, const float* __restrict__ raw1,
    const float* __restrict__ kvt0r, const float* __restrict__ kvt1r,
    const float* __restrict__ ssS, const float* __restrict__ ssSS,
    const float* __restrict__ wsum, const float* __restrict__ mean_w,
    const float* __restrict__ var_w, const float* __restrict__ snw,
    const float* __restrict__ snb, float* __restrict__ out)
{
    const int ch = blockIdx.x;   // 0..15
    const int bc = blockIdx.y;   // 0..23
    const int tid = threadIdx.x, lane = tid & 63, wave = tid >> 6;
    const int b = bc / 3, c = bc % 3;
    const float Nf = (float)Nn;

    // --- inline SwitchNorm stats (uniform across threads) ---
    float mln = 0.f, tln = 0.f;
#pragma unroll
    for (int cc = 0; cc < 3; ++cc) {
        float S = ssS[b * 3 + cc], SS = ssSS[b * 3 + cc];
        float m = S / Nf;
        float v = (SS - S * m) / (Nf - 1.0f);
        mln += m; tln += v + m * m;
    }
    mln *= (1.0f / 3.0f); tln *= (1.0f / 3.0f);
    const float vln = tln - mln * mln;
    float mbn = 0.f, tbn = 0.f;
#pragma unroll
    for (int bb2 = 0; bb2 < 8; ++bb2) {
        float S = ssS[bb2 * 3 + c], SS = ssSS[bb2 * 3 + c];
        float m = S / Nf;
        float v = (SS - S * m) / (Nf - 1.0f);
        mbn += m; tbn += v + m * m;
    }
    mbn *= 0.125f; tbn *= 0.125f;
    const float vbn = tbn - mbn * mbn;
    const float S_own = ssS[bc], SS_own = ssSS[bc];
    const float mean_in = S_own / Nf;
    const float var_in = (SS_own - S_own * mean_in) / (Nf - 1.0f);
    float mw0, mw1, mw2, vw0, vw1, vw2;
    {
        float m0 = mean_w[0], m1 = mean_w[1], m2 = mean_w[2];
        float mm = fmaxf(m0, fmaxf(m1, m2));
        float e0 = __expf(m0 - mm), e1 = __expf(m1 - mm), e2 = __expf(m2 - mm);
        float inv = 1.0f / (e0 + e1 + e2);
        mw0 = e0 * inv; mw1 = e1 * inv; mw2 = e2 * inv;
    }
    {
        float v0 = var_w[0], v1 = var_w[1], v2 = var_w[2];
        float vm = fmaxf(v0, fmaxf(v1, v2));
        float e0 = __expf(v0 - vm), e1 = __expf(v1 - vm), e2 = __expf(v2 - vm);
        float inv = 1.0f / (e0 + e1 + e2);
        vw0 = e0 * inv; vw1 = e1 * inv; vw2 = e2 * inv;
    }
    const float mean = mw0 * mean_in + mw1 * mln + mw2 * mbn;
    const float var  = vw0 * var_in + vw1 * vln + vw2 * vbn;
    const float sc = snw[c] / sqrtf(var + EPSn);
    const float sf = snb[c] - mean * sc;
    const float c0 = sf * wsum[2], c1 = sf * wsum[3];
    const float Wt0 = wsum[0], Wt1 = wsum[1];

    // --- A row (lanes 0..31 of wave 0; shuffle softmax over 32) ---
    __shared__ float aSh[Tn];
    if (tid < Tn) {
        float k0 = sc * kvt0r[bc * Tn + tid] + sf * Wt0;
        float k1 = sc * kvt1r[bc * Tn + tid] + sf * Wt1;
        float m = k0;
#pragma unroll
        for (int d = 1; d < 32; d <<= 1) m = fmaxf(m, __shfl_xor(m, d, 64));
        float e = __expf(k0 - m);
        float s = e;
#pragma unroll
        for (int d = 1; d < 32; d <<= 1) s += __shfl_xor(s, d, 64);
        aSh[tid] = sqrtf(e / s) * k1;
    }

    // --- s-softmax row max (sweep both raw halves) ---
    const float* p0a = raw0 + (size_t)bc * HWn;
    const float* p0b = p0a + (size_t)24 * HWn;
    float mloc = -3.4e38f;
#pragma unroll
    for (int i = 0; i < 16; ++i) {
        const int idx = tid * 4 + i * 1024;
        float4 u = *(const float4*)(p0a + idx);
        float4 v = *(const float4*)(p0b + idx);
        mloc = fmaxf(mloc, fmaxf(fmaxf(sc * (u.x + v.x) + c0, sc * (u.y + v.y) + c0),
                                 fmaxf(sc * (u.z + v.z) + c0, sc * (u.w + v.w) + c0)));
    }
#pragma unroll
    for (int d = 1; d < 64; d <<= 1) mloc = fmaxf(mloc, __shfl_xor(mloc, d, 64));
    __shared__ float wred[4];
    if (lane == 0) wred[wave] = mloc;
    __syncthreads();
    const float M = fmaxf(fmaxf(wred[0], wred[1]), fmaxf(wred[2], wred[3]));
    __syncthreads();
    // --- expsum sweep (re-read, L1/L2-hot) ---
    float sloc = 0.f;
#pragma unroll
    for (int i = 0; i < 16; ++i) {
        const int idx = tid * 4 + i * 1024;
        float4 u = *(const float4*)(p0a + idx);
        float4 v = *(const float4*)(p0b + idx);
        sloc += __expf(sc * (u.x + v.x) + c0 - M) + __expf(sc * (u.y + v.y) + c0 - M)
              + __expf(sc * (u.z + v.z) + c0 - M) + __expf(sc * (u.w + v.w) + c0 - M);
    }
#pragma unroll
    for (int d = 1; d < 64; d <<= 1) sloc += __shfl_xor(sloc, d, 64);
    if (lane == 0) wred[wave] = sloc;
    __syncthreads();
    const float Sexp = (wred[0] + wred[1]) + (wred[2] + wred[3]);
    const float invS = __builtin_amdgcn_rcpf(Sexp);

    // --- own 1024-px slice: B then outer product ---
    const int s = ch * 1024 + tid * 4;
    const float* p1a = raw1 + (size_t)bc * HWn;
    const float* p1b = p1a + (size_t)24 * HWn;
    float4 u0 = *(const float4*)(p0a + s), v0 = *(const float4*)(p0b + s);
    float4 u1 = *(const float4*)(p1a + s), v1 = *(const float4*)(p1b + s);
    float4 Bv;
    Bv.x = sqrtf(__expf(sc * (u0.x + v0.x) + c0 - M) * invS) * (sc * (u1.x + v1.x) + c1);
    Bv.y = sqrtf(__expf(sc * (u0.y + v0.y) + c0 - M) * invS) * (sc * (u1.y + v1.y) + c1);
    Bv.z = sqrtf(__expf(sc * (u0.z + v0.z) + c0 - M) * invS) * (sc * (u1.z + v1.z) + c1);
    Bv.w = sqrtf(__expf(sc * (u0.w + v0.w) + c0 - M) * invS) * (sc * (u1.w + v1.w) + c1);
    float* op = out + (size_t)bc * Nn + s;
#pragma unroll
    for (int t = 0; t < Tn; ++t) {
        const float av = aSh[t];
        float4 o; o.x = av * Bv.x; o.y = av * Bv.y; o.z = av * Bv.z; o.w = av * Bv.w;
        *(float4*)(op + (size_t)t * HWn) = o;
    }
}

extern "C" void kernel_launch(void* const* d_in, const int* in_sizes, int n_in,
                              void* d_out, int out_size, void* d_ws, size_t ws_size,
                              hipStream_t stream) {
    const float* x          = (const float*)d_in[0];
    const float* w_spatial  = (const float*)d_in[1];
    const float* b_spatial  = (const float*)d_in[2];
    const float* w_temporal = (const float*)d_in[3];
    const float* b_temporal = (const float*)d_in[4];
    const float* sn_weight  = (const float*)d_in[5];
    const float* sn_bias    = (const float*)d_in[6];
    const float* mean_weight= (const float*)d_in[7];
    const float* var_weight = (const float*)d_in[8];
    const float* w_kv_s     = (const float*)d_in[9];
    const float* w_kv_t     = (const float*)d_in[10];
    float* out = (float*)d_out;
    float* ws  = (float*)d_ws;

    // ws layout (floats) — y staged in fp16
    __half* yh   = (__half*)ws;                          // 12,582,912 halves = 6,291,456 f
    float* raw0  = ws + 6291456;                         // [QT][24][HWn] = 786432
    float* raw1  = raw0 + (size_t)QT * Bn * Cn * HWn;    // 786432
    float* pt0p  = raw1 + (size_t)QT * Bn * Cn * HWn;    // 24*32*128 = 98304
    float* pt1p  = pt0p + (size_t)Bn * Cn * Tn * SCH;    // 98304
    float* ss0p  = pt1p + (size_t)Bn * Cn * Tn * SCH;    // 24*256 = 6144
    float* ss1p  = ss0p + (size_t)Bn * Cn * SSW;         // 6144
    float* kvt0r = ss1p + (size_t)Bn * Cn * SSW;         // 768
    float* kvt1r = kvt0r + Bn * Cn * Tn;                 // 768
    float* ssS   = kvt1r + Bn * Cn * Tn;                 // 24
    float* ssSS  = ssS + 24;                             // 24
    float* wsum  = ssSS + 24;                            // 4

    k1_spatial<<<dim3(Bn * Tn, Hn / 8), 256, 0, stream>>>(x, w_spatial, b_spatial, yh);
    k2_temporal<<<dim3(SCH / 2, Bn * Cn, QT), 128, 0, stream>>>(yh, w_temporal,
                                                                b_temporal, w_kv_t,
                                                                w_kv_s, raw0, raw1,
                                                                pt0p, pt1p, ss0p, ss1p);
    k3a_reduce<<<Bn * Cn + 1, 256, 0, stream>>>(pt0p, pt1p, ss0p, ss1p, w_kv_t, w_kv_s,
                                                kvt0r, kvt1r, ssS, ssSS, wsum);
    k6_fused<<<dim3(16, Bn * Cn), 256, 0, stream>>>(raw0, raw1, kvt0r, kvt1r,
                                                    ssS, ssSS, wsum, mean_weight,
                                                    var_weight, sn_weight, sn_bias, out);
}

// Round 14
// 55.440 us; speedup vs baseline: 1.1976x; 1.1474x over previous
//
#include <hip/hip_runtime.h>
#include <hip/hip_bf16.h>
#include <hip/hip_fp16.h>

#define Bn 8
#define Cn 3
#define Tn 32
#define Hn 128
#define Wn 128
#define HWn (Hn * Wn)          // 16384
#define Nn (Tn * HWn)          // 524288 elems per (b,c)
#define EPSn 1e-5f
#define QT 4                   // 4-way t-split in k2 (8 outputs each)
#define SCH 128                // s-chunks per (b,c) in k2 (128 px each)
#define SSW (SCH * QT)         // 512 ss-partials per bc

__device__ __forceinline__ float silu_f(float v) {
    return v * __builtin_amdgcn_rcpf(1.0f + __expf(-v));
}

// ========== K1: spatial 3x3 conv (1->3ch) + SiLU -> y (fp16), 4 px/thread ==========
__global__ __launch_bounds__(256) void k1_spatial(
    const float* __restrict__ x, const float* __restrict__ wsp,
    const float* __restrict__ bsp, __half* __restrict__ y)
{
    const int tid = threadIdx.x;
    const int sub = tid & 31;           // 32 lane-groups of 4 px
    const int bt = blockIdx.x;          // 0..255
    const int b = bt >> 5, t = bt & 31;
    const int row = blockIdx.y * 8 + (tid >> 5);
    const int col = sub * 4;

    float w[27], bb[3];
#pragma unroll
    for (int i = 0; i < 27; ++i) w[i] = wsp[i];
#pragma unroll
    for (int i = 0; i < 3; ++i) bb[i] = bsp[i];

    const float* xsl = x + ((size_t)b * Tn + t) * HWn + (size_t)row * Wn + col;
    const bool upok = row > 0, dnok = row < Hn - 1;
    const float4 z4 = make_float4(0.f, 0.f, 0.f, 0.f);
    float4 xm = upok ? *(const float4*)(xsl - Wn) : z4;
    float4 xc = *(const float4*)(xsl);
    float4 xp = dnok ? *(const float4*)(xsl + Wn) : z4;
    float xv[3][6];
    {
        float lu, rd;
        lu = __shfl_up(xm.w, 1);  rd = __shfl_down(xm.x, 1);
        xv[0][0] = (sub == 0) ? 0.f : lu; xv[0][1] = xm.x; xv[0][2] = xm.y;
        xv[0][3] = xm.z; xv[0][4] = xm.w; xv[0][5] = (sub == 31) ? 0.f : rd;
        lu = __shfl_up(xc.w, 1);  rd = __shfl_down(xc.x, 1);
        xv[1][0] = (sub == 0) ? 0.f : lu; xv[1][1] = xc.x; xv[1][2] = xc.y;
        xv[1][3] = xc.z; xv[1][4] = xc.w; xv[1][5] = (sub == 31) ? 0.f : rd;
        lu = __shfl_up(xp.w, 1);  rd = __shfl_down(xp.x, 1);
        xv[2][0] = (sub == 0) ? 0.f : lu; xv[2][1] = xp.x; xv[2][2] = xp.y;
        xv[2][3] = xp.z; xv[2][4] = xp.w; xv[2][5] = (sub == 31) ? 0.f : rd;
    }
#pragma unroll
    for (int c = 0; c < 3; ++c) {
        float s0 = bb[c], s1 = bb[c], s2 = bb[c], s3 = bb[c];
#pragma unroll
        for (int i = 0; i < 3; ++i) {
#pragma unroll
            for (int j = 0; j < 3; ++j) {
                const float wv = w[c * 9 + i * 3 + j];
                s0 += wv * xv[i][j];
                s1 += wv * xv[i][j + 1];
                s2 += wv * xv[i][j + 2];
                s3 += wv * xv[i][j + 3];
            }
        }
        __half2 o01 = __floats2half2_rn(silu_f(s0), silu_f(s1));
        __half2 o23 = __floats2half2_rn(silu_f(s2), silu_f(s3));
        __half2* dst = (__half2*)(y + ((size_t)(b * 3 + c) * Tn + t) * HWn
                                  + (size_t)row * Wn + col);
        dst[0] = o01; dst[1] = o23;
    }
}

// ========== K2: temporal 7-tap conv from fp16 y + SiLU^2 + analytics ==========
// Wave = one 128-px chunk x one t-quarter (8 outputs). ZERO in-loop shuffles:
// per-t pt contributions held in registers (pt0a/pt1a[8]); ONE packed cross-lane
// reduce at kernel end (~65 shuffles vs ~150 with per-t reduction).
template<int QTg>
__device__ __forceinline__ void k2_body(
    const __half* __restrict__ y, const float* __restrict__ wtp,
    const float* __restrict__ btp, const float* __restrict__ wkt,
    const float* __restrict__ wks,
    float* __restrict__ raw0, float* __restrict__ raw1,
    float* __restrict__ pt0p, float* __restrict__ pt1p,
    float* __restrict__ ss0p, float* __restrict__ ss1p)
{
    constexpr int O0 = QTg * 8;
    constexpr int O1 = O0 + 8;
    constexpr int SLO = (O0 - 3 < 0) ? 0 : (O0 - 3);
    constexpr int SHI = (O1 + 2 > Tn - 1) ? (Tn - 1) : (O1 + 2);

    const int tid = threadIdx.x, lane = tid & 63, wave = tid >> 6;
    const int sch = blockIdx.x * 4 + wave;   // 0..127
    const int bc  = blockIdx.y;              // 0..23
    const int c = bc % 3;
    const int s0i = sch * 128 + lane * 2;

    float wt_r[7];
#pragma unroll
    for (int i = 0; i < 7; ++i) wt_r[i] = wtp[c * 7 + i];
    const float bt_r = btp[c];

    const __half* yb = y + (size_t)bc * Nn + s0i;
    const float2 k0v = *(const float2*)(wkt + s0i);
    const float2 k1v = *(const float2*)(wkt + HWn + s0i);

    float2 ring[7];
    float2 a0 = make_float2(0.f, 0.f), a1 = make_float2(0.f, 0.f);
    float ps = 0.f, pq = 0.f;
    float pt0a[8], pt1a[8];

#pragma unroll
    for (int tt = SLO; tt <= SHI + 3; ++tt) {
        if (tt <= SHI) {
            const __half2 hv = *(const __half2*)(yb + (size_t)tt * HWn);
            ring[tt % 7] = __half22float2(hv);
        }
        const int to = tt - 3;
        if (to >= O0 && to < O1) {          // compile-time pruned per unrolled iter
            float t0 = bt_r, t1 = bt_r;
#pragma unroll
            for (int k = 0; k < 7; ++k) {
                const int ts = to + k - 3;
                if (ts >= 0 && ts < Tn) {   // compile-time
                    const float wv = wt_r[k];
                    t0 += wv * ring[ts % 7].x;
                    t1 += wv * ring[ts % 7].y;
                }
            }
            const float g0 = silu_f(silu_f(t0));
            const float g1 = silu_f(silu_f(t1));
            const float wk0 = wks[to];      // uniform scalar loads
            const float wk1 = wks[Tn + to];
            a0.x += wk0 * g0; a0.y += wk0 * g1;
            a1.x += wk1 * g0; a1.y += wk1 * g1;
            ps += g0 + g1;
            pq += g0 * g0 + g1 * g1;
            pt0a[to - O0] = k0v.x * g0 + k0v.y * g1;   // per-lane, reduced at end
            pt1a[to - O0] = k1v.x * g0 + k1v.y * g1;
        }
    }

    // --- end-of-kernel packed cross-lane reduce ---
#pragma unroll
    for (int i = 0; i < 8; ++i) {
        pt0a[i] += __shfl_xor(pt0a[i], 1, 64);
        pt0a[i] += __shfl_xor(pt0a[i], 2, 64);
        pt0a[i] += __shfl_xor(pt0a[i], 4, 64);
        pt1a[i] += __shfl_xor(pt1a[i], 1, 64);
        pt1a[i] += __shfl_xor(pt1a[i], 2, 64);
        pt1a[i] += __shfl_xor(pt1a[i], 4, 64);
    }
    {
        const int j = lane & 7;
        float r0 = (j == 0) ? pt0a[0] : (j == 1) ? pt0a[1] : (j == 2) ? pt0a[2]
                 : (j == 3) ? pt0a[3] : (j == 4) ? pt0a[4] : (j == 5) ? pt0a[5]
                 : (j == 6) ? pt0a[6] : pt0a[7];
        float r1 = (j == 0) ? pt1a[0] : (j == 1) ? pt1a[1] : (j == 2) ? pt1a[2]
                 : (j == 3) ? pt1a[3] : (j == 4) ? pt1a[4] : (j == 5) ? pt1a[5]
                 : (j == 6) ? pt1a[6] : pt1a[7];
        r0 += __shfl_xor(r0, 8, 64); r0 += __shfl_xor(r0, 16, 64); r0 += __shfl_xor(r0, 32, 64);
        r1 += __shfl_xor(r1, 8, 64); r1 += __shfl_xor(r1, 16, 64); r1 += __shfl_xor(r1, 32, 64);
        if (lane < 8)
            pt0p[((size_t)bc * Tn + O0 + lane) * SCH + sch] = r0;
        else if (lane < 16)
            pt1p[((size_t)bc * Tn + O0 + (lane & 7)) * SCH + sch] = r1;
    }
    {
        float p0 = ps, p1 = pq;
        p0 += __shfl_xor(p0, 1, 64); p0 += __shfl_xor(p0, 2, 64); p0 += __shfl_xor(p0, 4, 64);
        p1 += __shfl_xor(p1, 1, 64); p1 += __shfl_xor(p1, 2, 64); p1 += __shfl_xor(p1, 4, 64);
        float r = (lane & 1) ? p1 : p0;
        r += __shfl_xor(r, 8, 64);
        r += __shfl_xor(r, 16, 64);
        r += __shfl_xor(r, 32, 64);
        if (lane == 0) ss0p[(size_t)bc * SSW + sch * QT + QTg] = r;
        if (lane == 1) ss1p[(size_t)bc * SSW + sch * QT + QTg] = r;
    }
    {
        const size_t off = (size_t)(QTg * 24 + bc) * HWn + s0i;
        *(float2*)(raw0 + off) = a0;
        *(float2*)(raw1 + off) = a1;
    }
}

__global__ __launch_bounds__(256) void k2_temporal(
    const __half* __restrict__ y, const float* __restrict__ wtp,
    const float* __restrict__ btp, const float* __restrict__ wkt,
    const float* __restrict__ wks,
    float* __restrict__ raw0, float* __restrict__ raw1,
    float* __restrict__ pt0p, float* __restrict__ pt1p,
    float* __restrict__ ss0p, float* __restrict__ ss1p)
{
    switch (blockIdx.z) {
    case 0: k2_body<0>(y, wtp, btp, wkt, wks, raw0, raw1, pt0p, pt1p, ss0p, ss1p); break;
    case 1: k2_body<1>(y, wtp, btp, wkt, wks, raw0, raw1, pt0p, pt1p, ss0p, ss1p); break;
    case 2: k2_body<2>(y, wtp, btp, wkt, wks, raw0, raw1, pt0p, pt1p, ss0p, ss1p); break;
    default: k2_body<3>(y, wtp, btp, wkt, wks, raw0, raw1, pt0p, pt1p, ss0p, ss1p); break;
    }
}

// ========== K3a: partial reductions + wkt/wks sums + raw quarter pre-sum ==========
// blocks 0..23: per-bc pt/ss reduce; block 24: weight sums; blocks 25..216: raw sum.
__global__ __launch_bounds__(256) void k3a_reduce(
    const float* __restrict__ pt0p, const float* __restrict__ pt1p,
    const float* __restrict__ ss0p, const float* __restrict__ ss1p,
    const float* __restrict__ wkt, const float* __restrict__ wks,
    const float* __restrict__ raw0, const float* __restrict__ raw1,
    float* __restrict__ kvt0r, float* __restrict__ kvt1r,
    float* __restrict__ ssS, float* __restrict__ ssSS, float* __restrict__ wsum,
    float* __restrict__ v0s, float* __restrict__ v1s)
{
    const int blk = blockIdx.x;
    const int tid = threadIdx.x;
    if (blk < Bn * Cn) {
        const int t = tid >> 3, g = tid & 7;
        const float4* p0 = (const float4*)(pt0p + ((size_t)blk * Tn + t) * SCH) + g * 4;
        const float4* p1 = (const float4*)(pt1p + ((size_t)blk * Tn + t) * SCH) + g * 4;
        float4 A0 = p0[0], A1 = p0[1], A2 = p0[2], A3 = p0[3];
        float4 B0 = p1[0], B1 = p1[1], B2 = p1[2], B3 = p1[3];
        float s0 = ((A0.x + A0.y) + (A0.z + A0.w)) + ((A1.x + A1.y) + (A1.z + A1.w))
                 + ((A2.x + A2.y) + (A2.z + A2.w)) + ((A3.x + A3.y) + (A3.z + A3.w));
        float s1 = ((B0.x + B0.y) + (B0.z + B0.w)) + ((B1.x + B1.y) + (B1.z + B1.w))
                 + ((B2.x + B2.y) + (B2.z + B2.w)) + ((B3.x + B3.y) + (B3.z + B3.w));
        s0 += __shfl_xor(s0, 1, 64); s0 += __shfl_xor(s0, 2, 64); s0 += __shfl_xor(s0, 4, 64);
        s1 += __shfl_xor(s1, 1, 64); s1 += __shfl_xor(s1, 2, 64); s1 += __shfl_xor(s1, 4, 64);
        if (g == 0) { kvt0r[blk * Tn + t] = s0; kvt1r[blk * Tn + t] = s1; }
        // ss reduce: SSW=512 floats each array (128 float4)
        const float4* q0 = (const float4*)(ss0p + (size_t)blk * SSW);
        const float4* q1 = (const float4*)(ss1p + (size_t)blk * SSW);
        float a = 0.f, bb = 0.f;
        if (tid < SSW / 4) {
            float4 a4 = q0[tid], b4 = q1[tid];
            a = (a4.x + a4.y) + (a4.z + a4.w);
            bb = (b4.x + b4.y) + (b4.z + b4.w);
        }
        __shared__ float r0[256], r1[256];
        r0[tid] = a; r1[tid] = bb;
        __syncthreads();
        for (int off = 128; off > 0; off >>= 1) {
            if (tid < off) { r0[tid] += r0[tid + off]; r1[tid] += r1[tid + off]; }
            __syncthreads();
        }
        if (tid == 0) { ssS[blk] = r0[0]; ssSS[blk] = r1[0]; }
    } else if (blk == Bn * Cn) {
        const float4* w0 = (const float4*)wkt;
        const float4* w1 = (const float4*)(wkt + HWn);
        float l0 = 0.f, l1 = 0.f;
        for (int i = tid; i < HWn / 4; i += 256) {
            float4 t0 = w0[i], t1 = w1[i];
            l0 += (t0.x + t0.y) + (t0.z + t0.w);
            l1 += (t1.x + t1.y) + (t1.z + t1.w);
        }
        __shared__ float r0[256], r1[256];
        r0[tid] = l0; r1[tid] = l1;
        __syncthreads();
        for (int off = 128; off > 0; off >>= 1) {
            if (tid < off) { r0[tid] += r0[tid + off]; r1[tid] += r1[tid + off]; }
            __syncthreads();
        }
        if (tid == 0) { wsum[0] = r0[0]; wsum[1] = r1[0]; }
        if (tid < 64) {
            float v = wks[tid];
            v += __shfl_xor(v, 1, 64); v += __shfl_xor(v, 2, 64);
            v += __shfl_xor(v, 4, 64); v += __shfl_xor(v, 8, 64);
            v += __shfl_xor(v, 16, 64);
            if (tid == 0) wsum[2] = v;
            if (tid == 32) wsum[3] = v;
        }
    } else {
        // raw quarter pre-sum: 192 blocks = 24 bc x 8 slices of 2048 px
        const int rs = blk - (Bn * Cn + 1);
        const int bc = rs >> 3, sl = rs & 7;
        const size_t idx = (size_t)bc * HWn + sl * 2048 + tid * 8;
        float4 a0 = make_float4(0.f, 0.f, 0.f, 0.f), a1 = a0, b0 = a0, b1 = a0;
#pragma unroll
        for (int q = 0; q < QT; ++q) {
            const float* p0 = raw0 + (size_t)q * 24 * HWn + idx;
            const float* p1 = raw1 + (size_t)q * 24 * HWn + idx;
            float4 t0 = ((const float4*)p0)[0], t1 = ((const float4*)p0)[1];
            float4 u0 = ((const float4*)p1)[0], u1 = ((const float4*)p1)[1];
            a0.x += t0.x; a0.y += t0.y; a0.z += t0.z; a0.w += t0.w;
            a1.x += t1.x; a1.y += t1.y; a1.z += t1.z; a1.w += t1.w;
            b0.x += u0.x; b0.y += u0.y; b0.z += u0.z; b0.w += u0.w;
            b1.x += u1.x; b1.y += u1.y; b1.z += u1.z; b1.w += u1.w;
        }
        ((float4*)(v0s + idx))[0] = a0; ((float4*)(v0s + idx))[1] = a1;
        ((float4*)(v1s + idx))[0] = b0; ((float4*)(v1s + idx))[1] = b1;
    }
}

// ========== K6: inline stats + A-softmax + s-softmax + outer product ==========
__global__ __launch_bounds__(256) void k6_fused(
    const float* __restrict__ v0s, const float* __restrict__ v1s,
    const float* __restrict__ kvt0r, const float* __restrict__ kvt1r,
    const float* __restrict__ ssS, const float* __restrict__ ssSS,
    const float* __restrict__ wsum, const float* __restrict__ mean_w,
    const float* __restrict__ var_w, const float* __restrict__ snw,
    const float* __restrict__ snb, float* __restrict__ out)
{
    const int ch = blockIdx.x;   // 0..15
    const int bc = blockIdx.y;   // 0..23
    const int tid = threadIdx.x, lane = tid & 63, wave = tid >> 6;
    const int b = bc / 3, c = bc % 3;
    const float Nf = (float)Nn;

    float mln = 0.f, tln = 0.f;
#pragma unroll
    for (int cc = 0; cc < 3; ++cc) {
        float S = ssS[b * 3 + cc], SS = ssSS[b * 3 + cc];
        float m = S / Nf;
        float v = (SS - S * m) / (Nf - 1.0f);
        mln += m; tln += v + m * m;
    }
    mln *= (1.0f / 3.0f); tln *= (1.0f / 3.0f);
    const float vln = tln - mln * mln;
    float mbn = 0.f, tbn = 0.f;
#pragma unroll
    for (int bb2 = 0; bb2 < 8; ++bb2) {
        float S = ssS[bb2 * 3 + c], SS = ssSS[bb2 * 3 + c];
        float m = S / Nf;
        float v = (SS - S * m) / (Nf - 1.0f);
        mbn += m; tbn += v + m * m;
    }
    mbn *= 0.125f; tbn *= 0.125f;
    const float vbn = tbn - mbn * mbn;
    const float S_own = ssS[bc], SS_own = ssSS[bc];
    const float mean_in = S_own / Nf;
    const float var_in = (SS_own - S_own * mean_in) / (Nf - 1.0f);
    float mw0, mw1, mw2, vw0, vw1, vw2;
    {
        float m0 = mean_w[0], m1 = mean_w[1], m2 = mean_w[2];
        float mm = fmaxf(m0, fmaxf(m1, m2));
        float e0 = __expf(m0 - mm), e1 = __expf(m1 - mm), e2 = __expf(m2 - mm);
        float inv = 1.0f / (e0 + e1 + e2);
        mw0 = e0 * inv; mw1 = e1 * inv; mw2 = e2 * inv;
    }
    {
        float v0 = var_w[0], v1 = var_w[1], v2 = var_w[2];
        float vm = fmaxf(v0, fmaxf(v1, v2));
        float e0 = __expf(v0 - vm), e1 = __expf(v1 - vm), e2 = __expf(v2 - vm);
        float inv = 1.0f / (e0 + e1 + e2);
        vw0 = e0 * inv; vw1 = e1 * inv; vw2 = e2 * inv;
    }
    const float mean = mw0 * mean_in + mw1 * mln + mw2 * mbn;
    const float var  = vw0 * var_in + vw1 * vln + vw2 * vbn;
    const float sc = snw[c] / sqrtf(var + EPSn);
    const float sf = snb[c] - mean * sc;
    const float c0 = sf * wsum[2], c1 = sf * wsum[3];
    const float Wt0 = wsum[0], Wt1 = wsum[1];

    __shared__ float aSh[Tn];
    if (tid < Tn) {
        float k0 = sc * kvt0r[bc * Tn + tid] + sf * Wt0;
        float k1 = sc * kvt1r[bc * Tn + tid] + sf * Wt1;
        float m = k0;
#pragma unroll
        for (int d = 1; d < 32; d <<= 1) m = fmaxf(m, __shfl_xor(m, d, 64));
        float e = __expf(k0 - m);
        float s = e;
#pragma unroll
        for (int d = 1; d < 32; d <<= 1) s += __shfl_xor(s, d, 64);
        aSh[tid] = sqrtf(e / s) * k1;
    }

    const float* p0a = v0s + (size_t)bc * HWn;
    float mloc = -3.4e38f;
#pragma unroll
    for (int i = 0; i < 16; ++i) {
        const int idx = tid * 4 + i * 1024;
        float4 u = *(const float4*)(p0a + idx);
        mloc = fmaxf(mloc, fmaxf(fmaxf(sc * u.x + c0, sc * u.y + c0),
                                 fmaxf(sc * u.z + c0, sc * u.w + c0)));
    }
#pragma unroll
    for (int d = 1; d < 64; d <<= 1) mloc = fmaxf(mloc, __shfl_xor(mloc, d, 64));
    __shared__ float wred[4];
    if (lane == 0) wred[wave] = mloc;
    __syncthreads();
    const float M = fmaxf(fmaxf(wred[0], wred[1]), fmaxf(wred[2], wred[3]));
    __syncthreads();
    float sloc = 0.f;
#pragma unroll
    for (int i = 0; i < 16; ++i) {
        const int idx = tid * 4 + i * 1024;
        float4 u = *(const float4*)(p0a + idx);
        sloc += __expf(sc * u.x + c0 - M) + __expf(sc * u.y + c0 - M)
              + __expf(sc * u.z + c0 - M) + __expf(sc * u.w + c0 - M);
    }
#pragma unroll
    for (int d = 1; d < 64; d <<= 1) sloc += __shfl_xor(sloc, d, 64);
    if (lane == 0) wred[wave] = sloc;
    __syncthreads();
    const float Sexp = (wred[0] + wred[1]) + (wred[2] + wred[3]);
    const float invS = __builtin_amdgcn_rcpf(Sexp);

    const int s = ch * 1024 + tid * 4;
    float4 u0 = *(const float4*)(p0a + s);
    float4 u1 = *(const float4*)(v1s + (size_t)bc * HWn + s);
    float4 Bv;
    Bv.x = sqrtf(__expf(sc * u0.x + c0 - M) * invS) * (sc * u1.x + c1);
    Bv.y = sqrtf(__expf(sc * u0.y + c0 - M) * invS) * (sc * u1.y + c1);
    Bv.z = sqrtf(__expf(sc * u0.z + c0 - M) * invS) * (sc * u1.z + c1);
    Bv.w = sqrtf(__expf(sc * u0.w + c0 - M) * invS) * (sc * u1.w + c1);
    float* op = out + (size_t)bc * Nn + s;
#pragma unroll
    for (int t = 0; t < Tn; ++t) {
        const float av = aSh[t];
        float4 o; o.x = av * Bv.x; o.y = av * Bv.y; o.z = av * Bv.z; o.w = av * Bv.w;
        *(float4*)(op + (size_t)t * HWn) = o;
    }
}

extern "C" void kernel_launch(void* const* d_in, const int* in_sizes, int n_in,
                              void* d_out, int out_size, void* d_ws, size_t ws_size,
                              hipStream_t stream) {
    const float* x          = (const float*)d_in[0];
    const float* w_spatial  = (const float*)d_in[1];
    const float* b_spatial  = (const float*)d_in[2];
    const float* w_temporal = (const float*)d_in[3];
    const float* b_temporal = (const float*)d_in[4];
    const float* sn_weight  = (const float*)d_in[5];
    const float* sn_bias    = (const float*)d_in[6];
    const float* mean_weight= (const float*)d_in[7];
    const float* var_weight = (const float*)d_in[8];
    const float* w_kv_s     = (const float*)d_in[9];
    const float* w_kv_t     = (const float*)d_in[10];
    float* out = (float*)d_out;
    float* ws  = (float*)d_ws;

    // ws layout (floats)
    __half* yh   = (__half*)ws;                          // 12.58M halves = 6,291,456 f
    float* raw0  = ws + 6291456;                         // [QT][24][HWn] = 1572864
    float* raw1  = raw0 + (size_t)QT * Bn * Cn * HWn;    // 1572864
    float* pt0p  = raw1 + (size_t)QT * Bn * Cn * HWn;    // 98304
    float* pt1p  = pt0p + (size_t)Bn * Cn * Tn * SCH;    // 98304
    float* ss0p  = pt1p + (size_t)Bn * Cn * Tn * SCH;    // 24*512 = 12288
    float* ss1p  = ss0p + (size_t)Bn * Cn * SSW;         // 12288
    float* v0s   = ss1p + (size_t)Bn * Cn * SSW;         // 393216
    float* v1s   = v0s + (size_t)Bn * Cn * HWn;          // 393216
    float* kvt0r = v1s + (size_t)Bn * Cn * HWn;          // 768
    float* kvt1r = kvt0r + Bn * Cn * Tn;                 // 768
    float* ssS   = kvt1r + Bn * Cn * Tn;                 // 24
    float* ssSS  = ssS + 24;                             // 24
    float* wsum  = ssSS + 24;                            // 4

    k1_spatial<<<dim3(Bn * Tn, Hn / 8), 256, 0, stream>>>(x, w_spatial, b_spatial, yh);
    k2_temporal<<<dim3(SCH / 4, Bn * Cn, QT), 256, 0, stream>>>(yh, w_temporal,
                                                                b_temporal, w_kv_t,
                                                                w_kv_s, raw0, raw1,
                                                                pt0p, pt1p, ss0p, ss1p);
    k3a_reduce<<<Bn * Cn + 1 + 192, 256, 0, stream>>>(pt0p, pt1p, ss0p, ss1p,
                                                      w_kv_t, w_kv_s, raw0, raw1,
                                                      kvt0r, kvt1r, ssS, ssSS, wsum,
                                                      v0s, v1s);
    k6_fused<<<dim3(16, Bn * Cn), 256, 0, stream>>>(v0s, v1s, kvt0r, kvt1r,
                                                    ssS, ssSS, wsum, mean_weight,
                                                    var_weight, sn_weight, sn_bias, out);
}

// Round 17
// 54.115 us; speedup vs baseline: 1.2269x; 1.0245x over previous
//
#include <hip/hip_runtime.h>
#include <hip/hip_bf16.h>
#include <hip/hip_fp16.h>

#define Bn 8
#define Cn 3
#define Tn 32
#define Hn 128
#define Wn 128
#define HWn (Hn * Wn)          // 16384
#define Nn (Tn * HWn)          // 524288 elems per (b,c)
#define EPSn 1e-5f
#define QT 4                   // 4-way t-split in k2 (8 outputs each)
#define SCH 128                // s-chunks per (b,c) in k2 (128 px each)
#define SSW (SCH * QT)         // 512 ss-partials per bc

__device__ __forceinline__ float silu_f(float v) {
    return v * __builtin_amdgcn_rcpf(1.0f + __expf(-v));
}

// ========== K1: spatial 3x3 conv (1->3ch) + SiLU -> y (fp16), 4 px/thread ==========
__global__ __launch_bounds__(256) void k1_spatial(
    const float* __restrict__ x, const float* __restrict__ wsp,
    const float* __restrict__ bsp, __half* __restrict__ y)
{
    const int tid = threadIdx.x;
    const int sub = tid & 31;           // 32 lane-groups of 4 px
    const int bt = blockIdx.x;          // 0..255
    const int b = bt >> 5, t = bt & 31;
    const int row = blockIdx.y * 8 + (tid >> 5);
    const int col = sub * 4;

    float w[27], bb[3];
#pragma unroll
    for (int i = 0; i < 27; ++i) w[i] = wsp[i];
#pragma unroll
    for (int i = 0; i < 3; ++i) bb[i] = bsp[i];

    const float* xsl = x + ((size_t)b * Tn + t) * HWn + (size_t)row * Wn + col;
    const bool upok = row > 0, dnok = row < Hn - 1;
    const float4 z4 = make_float4(0.f, 0.f, 0.f, 0.f);
    float4 xm = upok ? *(const float4*)(xsl - Wn) : z4;
    float4 xc = *(const float4*)(xsl);
    float4 xp = dnok ? *(const float4*)(xsl + Wn) : z4;
    float xv[3][6];
    {
        float lu, rd;
        lu = __shfl_up(xm.w, 1);  rd = __shfl_down(xm.x, 1);
        xv[0][0] = (sub == 0) ? 0.f : lu; xv[0][1] = xm.x; xv[0][2] = xm.y;
        xv[0][3] = xm.z; xv[0][4] = xm.w; xv[0][5] = (sub == 31) ? 0.f : rd;
        lu = __shfl_up(xc.w, 1);  rd = __shfl_down(xc.x, 1);
        xv[1][0] = (sub == 0) ? 0.f : lu; xv[1][1] = xc.x; xv[1][2] = xc.y;
        xv[1][3] = xc.z; xv[1][4] = xc.w; xv[1][5] = (sub == 31) ? 0.f : rd;
        lu = __shfl_up(xp.w, 1);  rd = __shfl_down(xp.x, 1);
        xv[2][0] = (sub == 0) ? 0.f : lu; xv[2][1] = xp.x; xv[2][2] = xp.y;
        xv[2][3] = xp.z; xv[2][4] = xp.w; xv[2][5] = (sub == 31) ? 0.f : rd;
    }
#pragma unroll
    for (int c = 0; c < 3; ++c) {
        float s0 = bb[c], s1 = bb[c], s2 = bb[c], s3 = bb[c];
#pragma unroll
        for (int i = 0; i < 3; ++i) {
#pragma unroll
            for (int j = 0; j < 3; ++j) {
                const float wv = w[c * 9 + i * 3 + j];
                s0 += wv * xv[i][j];
                s1 += wv * xv[i][j + 1];
                s2 += wv * xv[i][j + 2];
                s3 += wv * xv[i][j + 3];
            }
        }
        __half2 o01 = __floats2half2_rn(silu_f(s0), silu_f(s1));
        __half2 o23 = __floats2half2_rn(silu_f(s2), silu_f(s3));
        __half2* dst = (__half2*)(y + ((size_t)(b * 3 + c) * Tn + t) * HWn
                                  + (size_t)row * Wn + col);
        dst[0] = o01; dst[1] = o23;
    }
}

// ========== K2: temporal 7-tap conv from fp16 y + SiLU^2 + analytics ==========
// Register-accumulated pt (no in-loop shuffles); raw kv_s partials stored fp16.
template<int QTg>
__device__ __forceinline__ void k2_body(
    const __half* __restrict__ y, const float* __restrict__ wtp,
    const float* __restrict__ btp, const float* __restrict__ wkt,
    const float* __restrict__ wks,
    __half* __restrict__ raw0, __half* __restrict__ raw1,
    float* __restrict__ pt0p, float* __restrict__ pt1p,
    float* __restrict__ ss0p, float* __restrict__ ss1p)
{
    constexpr int O0 = QTg * 8;
    constexpr int O1 = O0 + 8;
    constexpr int SLO = (O0 - 3 < 0) ? 0 : (O0 - 3);
    constexpr int SHI = (O1 + 2 > Tn - 1) ? (Tn - 1) : (O1 + 2);

    const int tid = threadIdx.x, lane = tid & 63, wave = tid >> 6;
    const int sch = blockIdx.x * 4 + wave;   // 0..127
    const int bc  = blockIdx.y;              // 0..23
    const int c = bc % 3;
    const int s0i = sch * 128 + lane * 2;

    float wt_r[7];
#pragma unroll
    for (int i = 0; i < 7; ++i) wt_r[i] = wtp[c * 7 + i];
    const float bt_r = btp[c];

    const __half* yb = y + (size_t)bc * Nn + s0i;
    const float2 k0v = *(const float2*)(wkt + s0i);
    const float2 k1v = *(const float2*)(wkt + HWn + s0i);

    float2 ring[7];
    float2 a0 = make_float2(0.f, 0.f), a1 = make_float2(0.f, 0.f);
    float ps = 0.f, pq = 0.f;
    float pt0a[8], pt1a[8];

#pragma unroll
    for (int tt = SLO; tt <= SHI + 3; ++tt) {
        if (tt <= SHI) {
            const __half2 hv = *(const __half2*)(yb + (size_t)tt * HWn);
            ring[tt % 7] = __half22float2(hv);
        }
        const int to = tt - 3;
        if (to >= O0 && to < O1) {          // compile-time pruned per unrolled iter
            float t0 = bt_r, t1 = bt_r;
#pragma unroll
            for (int k = 0; k < 7; ++k) {
                const int ts = to + k - 3;
                if (ts >= 0 && ts < Tn) {   // compile-time
                    const float wv = wt_r[k];
                    t0 += wv * ring[ts % 7].x;
                    t1 += wv * ring[ts % 7].y;
                }
            }
            const float g0 = silu_f(silu_f(t0));
            const float g1 = silu_f(silu_f(t1));
            const float wk0 = wks[to];      // uniform scalar loads
            const float wk1 = wks[Tn + to];
            a0.x += wk0 * g0; a0.y += wk0 * g1;
            a1.x += wk1 * g0; a1.y += wk1 * g1;
            ps += g0 + g1;
            pq += g0 * g0 + g1 * g1;
            pt0a[to - O0] = k0v.x * g0 + k0v.y * g1;   // per-lane, reduced at end
            pt1a[to - O0] = k1v.x * g0 + k1v.y * g1;
        }
    }

    // --- end-of-kernel packed cross-lane reduce ---
#pragma unroll
    for (int i = 0; i < 8; ++i) {
        pt0a[i] += __shfl_xor(pt0a[i], 1, 64);
        pt0a[i] += __shfl_xor(pt0a[i], 2, 64);
        pt0a[i] += __shfl_xor(pt0a[i], 4, 64);
        pt1a[i] += __shfl_xor(pt1a[i], 1, 64);
        pt1a[i] += __shfl_xor(pt1a[i], 2, 64);
        pt1a[i] += __shfl_xor(pt1a[i], 4, 64);
    }
    {
        const int j = lane & 7;
        float r0 = (j == 0) ? pt0a[0] : (j == 1) ? pt0a[1] : (j == 2) ? pt0a[2]
                 : (j == 3) ? pt0a[3] : (j == 4) ? pt0a[4] : (j == 5) ? pt0a[5]
                 : (j == 6) ? pt0a[6] : pt0a[7];
        float r1 = (j == 0) ? pt1a[0] : (j == 1) ? pt1a[1] : (j == 2) ? pt1a[2]
                 : (j == 3) ? pt1a[3] : (j == 4) ? pt1a[4] : (j == 5) ? pt1a[5]
                 : (j == 6) ? pt1a[6] : pt1a[7];
        r0 += __shfl_xor(r0, 8, 64); r0 += __shfl_xor(r0, 16, 64); r0 += __shfl_xor(r0, 32, 64);
        r1 += __shfl_xor(r1, 8, 64); r1 += __shfl_xor(r1, 16, 64); r1 += __shfl_xor(r1, 32, 64);
        if (lane < 8)
            pt0p[((size_t)bc * Tn + O0 + lane) * SCH + sch] = r0;
        else if (lane < 16)
            pt1p[((size_t)bc * Tn + O0 + (lane & 7)) * SCH + sch] = r1;
    }
    {
        float p0 = ps, p1 = pq;
        p0 += __shfl_xor(p0, 1, 64); p0 += __shfl_xor(p0, 2, 64); p0 += __shfl_xor(p0, 4, 64);
        p1 += __shfl_xor(p1, 1, 64); p1 += __shfl_xor(p1, 2, 64); p1 += __shfl_xor(p1, 4, 64);
        float r = (lane & 1) ? p1 : p0;
        r += __shfl_xor(r, 8, 64);
        r += __shfl_xor(r, 16, 64);
        r += __shfl_xor(r, 32, 64);
        if (lane == 0) ss0p[(size_t)bc * SSW + sch * QT + QTg] = r;
        if (lane == 1) ss1p[(size_t)bc * SSW + sch * QT + QTg] = r;
    }
    {
        const size_t off = (size_t)(QTg * 24 + bc) * HWn + s0i;
        *(__half2*)(raw0 + off) = __floats2half2_rn(a0.x, a0.y);
        *(__half2*)(raw1 + off) = __floats2half2_rn(a1.x, a1.y);
    }
}

__global__ __launch_bounds__(256) void k2_temporal(
    const __half* __restrict__ y, const float* __restrict__ wtp,
    const float* __restrict__ btp, const float* __restrict__ wkt,
    const float* __restrict__ wks,
    __half* __restrict__ raw0, __half* __restrict__ raw1,
    float* __restrict__ pt0p, float* __restrict__ pt1p,
    float* __restrict__ ss0p, float* __restrict__ ss1p)
{
    switch (blockIdx.z) {
    case 0: k2_body<0>(y, wtp, btp, wkt, wks, raw0, raw1, pt0p, pt1p, ss0p, ss1p); break;
    case 1: k2_body<1>(y, wtp, btp, wkt, wks, raw0, raw1, pt0p, pt1p, ss0p, ss1p); break;
    case 2: k2_body<2>(y, wtp, btp, wkt, wks, raw0, raw1, pt0p, pt1p, ss0p, ss1p); break;
    default: k2_body<3>(y, wtp, btp, wkt, wks, raw0, raw1, pt0p, pt1p, ss0p, ss1p); break;
    }
}

// ========== K3a: partial reductions + wkt/wks sums + raw quarter pre-sum (fp16) ==========
__global__ __launch_bounds__(256) void k3a_reduce(
    const float* __restrict__ pt0p, const float* __restrict__ pt1p,
    const float* __restrict__ ss0p, const float* __restrict__ ss1p,
    const float* __restrict__ wkt, const float* __restrict__ wks,
    const __half* __restrict__ raw0, const __half* __restrict__ raw1,
    float* __restrict__ kvt0r, float* __restrict__ kvt1r,
    float* __restrict__ ssS, float* __restrict__ ssSS, float* __restrict__ wsum,
    __half* __restrict__ v0s, __half* __restrict__ v1s)
{
    const int blk = blockIdx.x;
    const int tid = threadIdx.x;
    if (blk < Bn * Cn) {
        const int t = tid >> 3, g = tid & 7;
        const float4* p0 = (const float4*)(pt0p + ((size_t)blk * Tn + t) * SCH) + g * 4;
        const float4* p1 = (const float4*)(pt1p + ((size_t)blk * Tn + t) * SCH) + g * 4;
        float4 A0 = p0[0], A1 = p0[1], A2 = p0[2], A3 = p0[3];
        float4 B0 = p1[0], B1 = p1[1], B2 = p1[2], B3 = p1[3];
        float s0 = ((A0.x + A0.y) + (A0.z + A0.w)) + ((A1.x + A1.y) + (A1.z + A1.w))
                 + ((A2.x + A2.y) + (A2.z + A2.w)) + ((A3.x + A3.y) + (A3.z + A3.w));
        float s1 = ((B0.x + B0.y) + (B0.z + B0.w)) + ((B1.x + B1.y) + (B1.z + B1.w))
                 + ((B2.x + B2.y) + (B2.z + B2.w)) + ((B3.x + B3.y) + (B3.z + B3.w));
        s0 += __shfl_xor(s0, 1, 64); s0 += __shfl_xor(s0, 2, 64); s0 += __shfl_xor(s0, 4, 64);
        s1 += __shfl_xor(s1, 1, 64); s1 += __shfl_xor(s1, 2, 64); s1 += __shfl_xor(s1, 4, 64);
        if (g == 0) { kvt0r[blk * Tn + t] = s0; kvt1r[blk * Tn + t] = s1; }
        // ss reduce: SSW=512 floats each array (128 float4)
        const float4* q0 = (const float4*)(ss0p + (size_t)blk * SSW);
        const float4* q1 = (const float4*)(ss1p + (size_t)blk * SSW);
        float a = 0.f, bb = 0.f;
        if (tid < SSW / 4) {
            float4 a4 = q0[tid], b4 = q1[tid];
            a = (a4.x + a4.y) + (a4.z + a4.w);
            bb = (b4.x + b4.y) + (b4.z + b4.w);
        }
        __shared__ float r0[256], r1[256];
        r0[tid] = a; r1[tid] = bb;
        __syncthreads();
        for (int off = 128; off > 0; off >>= 1) {
            if (tid < off) { r0[tid] += r0[tid + off]; r1[tid] += r1[tid + off]; }
            __syncthreads();
        }
        if (tid == 0) { ssS[blk] = r0[0]; ssSS[blk] = r1[0]; }
    } else if (blk == Bn * Cn) {
        const float4* w0 = (const float4*)wkt;
        const float4* w1 = (const float4*)(wkt + HWn);
        float l0 = 0.f, l1 = 0.f;
        for (int i = tid; i < HWn / 4; i += 256) {
            float4 t0 = w0[i], t1 = w1[i];
            l0 += (t0.x + t0.y) + (t0.z + t0.w);
            l1 += (t1.x + t1.y) + (t1.z + t1.w);
        }
        __shared__ float r0[256], r1[256];
        r0[tid] = l0; r1[tid] = l1;
        __syncthreads();
        for (int off = 128; off > 0; off >>= 1) {
            if (tid < off) { r0[tid] += r0[tid + off]; r1[tid] += r1[tid + off]; }
            __syncthreads();
        }
        if (tid == 0) { wsum[0] = r0[0]; wsum[1] = r1[0]; }
        if (tid < 64) {
            float v = wks[tid];
            v += __shfl_xor(v, 1, 64); v += __shfl_xor(v, 2, 64);
            v += __shfl_xor(v, 4, 64); v += __shfl_xor(v, 8, 64);
            v += __shfl_xor(v, 16, 64);
            if (tid == 0) wsum[2] = v;
            if (tid == 32) wsum[3] = v;
        }
    } else {
        // raw quarter pre-sum: 192 blocks = 24 bc x 8 slices of 2048 px (fp16 in/out)
        const int rs = blk - (Bn * Cn + 1);
        const int bc = rs >> 3, sl = rs & 7;
        const size_t idx = (size_t)bc * HWn + sl * 2048 + tid * 8;
        float acc0[8] = {0,0,0,0,0,0,0,0}, acc1[8] = {0,0,0,0,0,0,0,0};
#pragma unroll
        for (int q = 0; q < QT; ++q) {
            float4 h0 = *(const float4*)(raw0 + (size_t)q * 24 * HWn + idx);
            float4 h1 = *(const float4*)(raw1 + (size_t)q * 24 * HWn + idx);
            const __half2* p0 = (const __half2*)&h0;
            const __half2* p1 = (const __half2*)&h1;
#pragma unroll
            for (int j = 0; j < 4; ++j) {
                float2 f0 = __half22float2(p0[j]);
                float2 f1 = __half22float2(p1[j]);
                acc0[j * 2] += f0.x; acc0[j * 2 + 1] += f0.y;
                acc1[j * 2] += f1.x; acc1[j * 2 + 1] += f1.y;
            }
        }
        float4 o0, o1;
        __half2* s0 = (__half2*)&o0; __half2* s1 = (__half2*)&o1;
#pragma unroll
        for (int j = 0; j < 4; ++j) {
            s0[j] = __floats2half2_rn(acc0[j * 2], acc0[j * 2 + 1]);
            s1[j] = __floats2half2_rn(acc1[j * 2], acc1[j * 2 + 1]);
        }
        *(float4*)(v0s + idx) = o0;
        *(float4*)(v1s + idx) = o1;
    }
}

// ========== K6: inline stats + A-softmax + single-sweep online s-softmax + outer ==========
__global__ __launch_bounds__(256) void k6_fused(
    const __half* __restrict__ v0s, const __half* __restrict__ v1s,
    const float* __restrict__ kvt0r, const float* __restrict__ kvt1r,
    const float* __restrict__ ssS, const float* __restrict__ ssSS,
    const float* __restrict__ wsum, const float* __restrict__ mean_w,
    const float* __restrict__ var_w, const float* __restrict__ snw,
    const float* __restrict__ snb, float* __restrict__ out)
{
    const int ch = blockIdx.x;   // 0..15
    const int bc = blockIdx.y;   // 0..23
    const int tid = threadIdx.x, lane = tid & 63, wave = tid >> 6;
    const int b = bc / 3, c = bc % 3;
    const float Nf = (float)Nn;

    float mln = 0.f, tln = 0.f;
#pragma unroll
    for (int cc = 0; cc < 3; ++cc) {
        float S = ssS[b * 3 + cc], SS = ssSS[b * 3 + cc];
        float m = S / Nf;
        float v = (SS - S * m) / (Nf - 1.0f);
        mln += m; tln += v + m * m;
    }
    mln *= (1.0f / 3.0f); tln *= (1.0f / 3.0f);
    const float vln = tln - mln * mln;
    float mbn = 0.f, tbn = 0.f;
#pragma unroll
    for (int bb2 = 0; bb2 < 8; ++bb2) {
        float S = ssS[bb2 * 3 + c], SS = ssSS[bb2 * 3 + c];
        float m = S / Nf;
        float v = (SS - S * m) / (Nf - 1.0f);
        mbn += m; tbn += v + m * m;
    }
    mbn *= 0.125f; tbn *= 0.125f;
    const float vbn = tbn - mbn * mbn;
    const float S_own = ssS[bc], SS_own = ssSS[bc];
    const float mean_in = S_own / Nf;
    const float var_in = (SS_own - S_own * mean_in) / (Nf - 1.0f);
    float mw0, mw1, mw2, vw0, vw1, vw2;
    {
        float m0 = mean_w[0], m1 = mean_w[1], m2 = mean_w[2];
        float mm = fmaxf(m0, fmaxf(m1, m2));
        float e0 = __expf(m0 - mm), e1 = __expf(m1 - mm), e2 = __expf(m2 - mm);
        float inv = 1.0f / (e0 + e1 + e2);
        mw0 = e0 * inv; mw1 = e1 * inv; mw2 = e2 * inv;
    }
    {
        float v0 = var_w[0], v1 = var_w[1], v2 = var_w[2];
        float vm = fmaxf(v0, fmaxf(v1, v2));
        float e0 = __expf(v0 - vm), e1 = __expf(v1 - vm), e2 = __expf(v2 - vm);
        float inv = 1.0f / (e0 + e1 + e2);
        vw0 = e0 * inv; vw1 = e1 * inv; vw2 = e2 * inv;
    }
    const float mean = mw0 * mean_in + mw1 * mln + mw2 * mbn;
    const float var  = vw0 * var_in + vw1 * vln + vw2 * vbn;
    const float sc = snw[c] / sqrtf(var + EPSn);
    const float sf = snb[c] - mean * sc;
    const float c0 = sf * wsum[2], c1 = sf * wsum[3];
    const float Wt0 = wsum[0], Wt1 = wsum[1];

    __shared__ float aSh[Tn];
    if (tid < Tn) {
        float k0 = sc * kvt0r[bc * Tn + tid] + sf * Wt0;
        float k1 = sc * kvt1r[bc * Tn + tid] + sf * Wt1;
        float m = k0;
#pragma unroll
        for (int d = 1; d < 32; d <<= 1) m = fmaxf(m, __shfl_xor(m, d, 64));
        float e = __expf(k0 - m);
        float s = e;
#pragma unroll
        for (int d = 1; d < 32; d <<= 1) s += __shfl_xor(s, d, 64);
        aSh[tid] = sqrtf(e / s) * k1;
    }

    // --- single-sweep online softmax stats over the bc row (fp16 v0s) ---
    const __half* p0a = v0s + (size_t)bc * HWn;
    float m_run = -3.4e38f, s_run = 0.f;
#pragma unroll
    for (int i = 0; i < 8; ++i) {
        const int idx = tid * 8 + i * 2048;         // 8 px per iter
        float4 hv = *(const float4*)(p0a + idx);
        const __half2* hp = (const __half2*)&hv;
        float vals[8];
#pragma unroll
        for (int j = 0; j < 4; ++j) {
            float2 f = __half22float2(hp[j]);
            vals[j * 2] = sc * f.x + c0;
            vals[j * 2 + 1] = sc * f.y + c0;
        }
        float vm = vals[0];
#pragma unroll
        for (int j = 1; j < 8; ++j) vm = fmaxf(vm, vals[j]);
        const float mn = fmaxf(m_run, vm);
        float sl = 0.f;
#pragma unroll
        for (int j = 0; j < 8; ++j) sl += __expf(vals[j] - mn);
        s_run = s_run * __expf(m_run - mn) + sl;
        m_run = mn;
    }
#pragma unroll
    for (int d = 1; d < 64; d <<= 1) {
        const float mo = __shfl_xor(m_run, d, 64);
        const float so = __shfl_xor(s_run, d, 64);
        const float mn = fmaxf(m_run, mo);
        s_run = s_run * __expf(m_run - mn) + so * __expf(mo - mn);
        m_run = mn;
    }
    __shared__ float wm[4], wsv[4];
    if (lane == 0) { wm[wave] = m_run; wsv[wave] = s_run; }
    __syncthreads();
    float M = fmaxf(fmaxf(wm[0], wm[1]), fmaxf(wm[2], wm[3]));
    float Sexp = wsv[0] * __expf(wm[0] - M) + wsv[1] * __expf(wm[1] - M)
               + wsv[2] * __expf(wm[2] - M) + wsv[3] * __expf(wm[3] - M);
    const float invS = __builtin_amdgcn_rcpf(Sexp);

    // --- own 1024-px slice: B then outer product ---
    const int s = ch * 1024 + tid * 4;
    float2 h0 = *(const float2*)(p0a + s);
    float2 h1 = *(const float2*)(v1s + (size_t)bc * HWn + s);
    const __half2* q0 = (const __half2*)&h0;
    const __half2* q1 = (const __half2*)&h1;
    float2 u0l = __half22float2(q0[0]), u0h = __half22float2(q0[1]);
    float2 u1l = __half22float2(q1[0]), u1h = __half22float2(q1[1]);
    float4 Bv;
    Bv.x = sqrtf(__expf(sc * u0l.x + c0 - M) * invS) * (sc * u1l.x + c1);
    Bv.y = sqrtf(__expf(sc * u0l.y + c0 - M) * invS) * (sc * u1l.y + c1);
    Bv.z = sqrtf(__expf(sc * u0h.x + c0 - M) * invS) * (sc * u1h.x + c1);
    Bv.w = sqrtf(__expf(sc * u0h.y + c0 - M) * invS) * (sc * u1h.y + c1);
    float* op = out + (size_t)bc * Nn + s;
#pragma unroll
    for (int t = 0; t < Tn; ++t) {
        const float av = aSh[t];
        float4 o; o.x = av * Bv.x; o.y = av * Bv.y; o.z = av * Bv.z; o.w = av * Bv.w;
        *(float4*)(op + (size_t)t * HWn) = o;
    }
}

extern "C" void kernel_launch(void* const* d_in, const int* in_sizes, int n_in,
                              void* d_out, int out_size, void* d_ws, size_t ws_size,
                              hipStream_t stream) {
    const float* x          = (const float*)d_in[0];
    const float* w_spatial  = (const float*)d_in[1];
    const float* b_spatial  = (const float*)d_in[2];
    const float* w_temporal = (const float*)d_in[3];
    const float* b_temporal = (const float*)d_in[4];
    const float* sn_weight  = (const float*)d_in[5];
    const float* sn_bias    = (const float*)d_in[6];
    const float* mean_weight= (const float*)d_in[7];
    const float* var_weight = (const float*)d_in[8];
    const float* w_kv_s     = (const float*)d_in[9];
    const float* w_kv_t     = (const float*)d_in[10];
    float* out = (float*)d_out;
    float* ws  = (float*)d_ws;

    // ws layout (floats)
    __half* yh   = (__half*)ws;                          // 12.58M halves = 6,291,456 f
    __half* raw0 = (__half*)(ws + 6291456);              // [QT][24][HWn] h = 786432 f
    __half* raw1 = raw0 + (size_t)QT * Bn * Cn * HWn;    // 786432 f
    float* pt0p  = ws + 6291456 + 2 * 786432;            // 98304
    float* pt1p  = pt0p + (size_t)Bn * Cn * Tn * SCH;    // 98304
    float* ss0p  = pt1p + (size_t)Bn * Cn * Tn * SCH;    // 12288
    float* ss1p  = ss0p + (size_t)Bn * Cn * SSW;         // 12288
    __half* v0s  = (__half*)(ss1p + (size_t)Bn * Cn * SSW);  // 24*HWn h = 196608 f
    __half* v1s  = v0s + (size_t)Bn * Cn * HWn;              // 196608 f
    float* kvt0r = (float*)(v1s + (size_t)Bn * Cn * HWn);    // 768
    float* kvt1r = kvt0r + Bn * Cn * Tn;                 // 768
    float* ssS   = kvt1r + Bn * Cn * Tn;                 // 24
    float* ssSS  = ssS + 24;                             // 24
    float* wsum  = ssSS + 24;                            // 4

    k1_spatial<<<dim3(Bn * Tn, Hn / 8), 256, 0, stream>>>(x, w_spatial, b_spatial, yh);
    k2_temporal<<<dim3(SCH / 4, Bn * Cn, QT), 256, 0, stream>>>(yh, w_temporal,
                                                                b_temporal, w_kv_t,
                                                                w_kv_s, raw0, raw1,
                                                                pt0p, pt1p, ss0p, ss1p);
    k3a_reduce<<<Bn * Cn + 1 + 192, 256, 0, stream>>>(pt0p, pt1p, ss0p, ss1p,
                                                      w_kv_t, w_kv_s, raw0, raw1,
                                                      kvt0r, kvt1r, ssS, ssSS, wsum,
                                                      v0s, v1s);
    k6_fused<<<dim3(16, Bn * Cn), 256, 0, stream>>>(v0s, v1s, kvt0r, kvt1r,
                                                    ssS, ssSS, wsum, mean_weight,
                                                    var_weight, sn_weight, sn_bias, out);
}